// Round 12
// baseline (798.149 us; speedup 1.0000x reference)
//
#include <hip/hip_runtime.h>
#include <cstdint>
#include <math.h>

// ---------------------------------------------------------------------------
// LlamaSelfAttentionBlock: rmsnorm -> QKV (rope-diag) -> causal attn -> +res
//                          -> rmsnorm -> w1+b1 -> silu(beta*gate)*lin -> w2+b2 -> +res
// fp16 MFMA, f32 accumulate. B=2,L=2048,E=2048,H=16,hd=128,F=4096.
// Round 12: gemm256 switched to v_mfma_f32_32x32x16_f16 (15% better cyc/FLOP,
// same LDS traffic / regs / schedule). gemm_k stays 16x16x32 (proven).
// attn: round-10 counted-vmcnt pipeline. x2 residual f16.
// ---------------------------------------------------------------------------

typedef _Float16 f16;
typedef _Float16 f16x8 __attribute__((ext_vector_type(8)));
typedef _Float16 f16x4 __attribute__((ext_vector_type(4)));
typedef float    f32x4 __attribute__((ext_vector_type(4)));
typedef float    f32x16 __attribute__((ext_vector_type(16)));

#define MFMA_16x16x32(a, b, c) __builtin_amdgcn_mfma_f32_16x16x32_f16(a, b, c, 0, 0, 0)
#define MFMA_32x32x16(a, b, c) __builtin_amdgcn_mfma_f32_32x32x16_f16(a, b, c, 0, 0, 0)

__device__ __forceinline__ void gload_lds16(const void* g, void* lds) {
  __builtin_amdgcn_global_load_lds(
      (__attribute__((address_space(1))) void*)(uintptr_t)g,
      (__attribute__((address_space(3))) void*)(unsigned)(uintptr_t)lds,
      16, 0, 0);
}

// ---------------------------------------------------------------------------
// f32 [K][N] -> fp16 [N][K] transpose+convert (32x32 LDS tile)
// ---------------------------------------------------------------------------
__global__ void convT_k(const float* __restrict__ W, f16* __restrict__ Wt,
                        int K, int N) {
  __shared__ float tile[32][33];
  const int n0 = blockIdx.x << 5, k0 = blockIdx.y << 5;
  const int t = threadIdx.x;
  const int r = t >> 3, c4 = (t & 7) << 2;
  const f32x4 v = *(const f32x4*)(W + (size_t)(k0 + r) * N + n0 + c4);
  tile[r][c4 + 0] = v[0]; tile[r][c4 + 1] = v[1];
  tile[r][c4 + 2] = v[2]; tile[r][c4 + 3] = v[3];
  __syncthreads();
  f16x4 o;
  o[0] = (f16)tile[c4 + 0][r]; o[1] = (f16)tile[c4 + 1][r];
  o[2] = (f16)tile[c4 + 2][r]; o[3] = (f16)tile[c4 + 3][r];
  *(f16x4*)(Wt + (size_t)(n0 + r) * K + k0 + c4) = o;
}

// ---------------------------------------------------------------------------
// rope diag table: D[l][d] = cos(l * 10000^(-2*(d/2)/128)), f32 [2048][128]
// ---------------------------------------------------------------------------
__global__ void rope_tab_k(float* __restrict__ Dt) {
  const int l = blockIdx.x, d = threadIdx.x;
  const float th = __expf(-0.0719557841f * (float)(d & ~1));
  Dt[(l << 7) + d] = cosf((float)l * th);
}

// ---------------------------------------------------------------------------
// RMSNorm (f32 input): one block (256 thr) per row of 2048
// ---------------------------------------------------------------------------
__global__ void rmsnorm_k(const float* __restrict__ X, const float* __restrict__ G,
                          f16* __restrict__ H) {
  __shared__ float red[4];
  const int row = blockIdx.x, t = threadIdx.x;
  const float* xp = X + ((size_t)row << 11) + (t << 3);
  const f32x4 v0 = *(const f32x4*)xp;
  const f32x4 v1 = *(const f32x4*)(xp + 4);
  float ss = v0[0]*v0[0] + v0[1]*v0[1] + v0[2]*v0[2] + v0[3]*v0[3]
           + v1[0]*v1[0] + v1[1]*v1[1] + v1[2]*v1[2] + v1[3]*v1[3];
#pragma unroll
  for (int m = 1; m < 64; m <<= 1) ss += __shfl_xor(ss, m);
  if ((t & 63) == 0) red[t >> 6] = ss;
  __syncthreads();
  const float tot = red[0] + red[1] + red[2] + red[3];
  const float rs = rsqrtf(tot * (1.f / 2048.f) + 1e-6f);
  const float* gp = G + (t << 3);
  const f32x4 g0 = *(const f32x4*)gp, g1 = *(const f32x4*)(gp + 4);
  f16x8 o;
  o[0] = (f16)(v0[0]*rs*g0[0]); o[1] = (f16)(v0[1]*rs*g0[1]);
  o[2] = (f16)(v0[2]*rs*g0[2]); o[3] = (f16)(v0[3]*rs*g0[3]);
  o[4] = (f16)(v1[0]*rs*g1[0]); o[5] = (f16)(v1[1]*rs*g1[1]);
  o[6] = (f16)(v1[2]*rs*g1[2]); o[7] = (f16)(v1[3]*rs*g1[3]);
  *(f16x8*)(H + ((size_t)row << 11) + (t << 3)) = o;
}

// ---------------------------------------------------------------------------
// RMSNorm (f16 input) — for the f16 x2 residual buffer
// ---------------------------------------------------------------------------
__global__ void rmsnorm_h_k(const f16* __restrict__ X, const float* __restrict__ G,
                            f16* __restrict__ H) {
  __shared__ float red[4];
  const int row = blockIdx.x, t = threadIdx.x;
  const f16x8 v = *(const f16x8*)(X + ((size_t)row << 11) + (t << 3));
  float f[8];
#pragma unroll
  for (int i = 0; i < 8; ++i) f[i] = (float)v[i];
  float ss = 0.f;
#pragma unroll
  for (int i = 0; i < 8; ++i) ss += f[i] * f[i];
#pragma unroll
  for (int m = 1; m < 64; m <<= 1) ss += __shfl_xor(ss, m);
  if ((t & 63) == 0) red[t >> 6] = ss;
  __syncthreads();
  const float tot = red[0] + red[1] + red[2] + red[3];
  const float rs = rsqrtf(tot * (1.f / 2048.f) + 1e-6f);
  const float* gp = G + (t << 3);
  const f32x4 g0 = *(const f32x4*)gp, g1 = *(const f32x4*)(gp + 4);
  f16x8 o;
#pragma unroll
  for (int i = 0; i < 4; ++i) o[i] = (f16)(f[i] * rs * g0[i]);
#pragma unroll
  for (int i = 0; i < 4; ++i) o[4 + i] = (f16)(f[4 + i] * rs * g1[i]);
  *(f16x8*)(H + ((size_t)row << 11) + (t << 3)) = o;
}

// ---------------------------------------------------------------------------
// per-head V transpose: V [B*L][E] -> Vt [B*H][128][2048]  (fp16)
// ---------------------------------------------------------------------------
__global__ void vtrans_k(const f16* __restrict__ V, f16* __restrict__ Vt) {
  __shared__ f16 tile[32][36];
  const int l0 = blockIdx.x << 5, d0 = blockIdx.y << 5, bh = blockIdx.z;
  const int b = bh >> 4, h = bh & 15;
  const int t = threadIdx.x;
  const int r = t >> 3, c4 = (t & 7) << 2;
  const f16x4 v = *(const f16x4*)(V + (size_t)((b << 11) + l0 + r) * 2048 + (h << 7) + d0 + c4);
  tile[r][c4 + 0] = v[0]; tile[r][c4 + 1] = v[1];
  tile[r][c4 + 2] = v[2]; tile[r][c4 + 3] = v[3];
  __syncthreads();
  f16x4 o;
  o[0] = tile[c4 + 0][r]; o[1] = tile[c4 + 1][r];
  o[2] = tile[c4 + 2][r]; o[3] = tile[c4 + 3][r];
  *(f16x4*)(Vt + (size_t)((bh << 7) + d0 + r) * 2048 + l0 + c4) = o;
}

// ---------------------------------------------------------------------------
// 256x256-tile 8-phase fp16 GEMM — round-4 schedule, MFMA 32x32x16.
// Frag layouts: A/B row=lane&31, k=(lane>>5)*8+j; C/D col=lane&31,
// row=(r&3)+8*(r>>2)+4*(lane>>5) [guide m74/m101, HW-verified].
// Same staging/vmcnt/barrier skeleton as rounds 4-11 (validated).
// EPI: 2=+bias  3=+bias,silu(beta)  4=+bias,*auxh
// ---------------------------------------------------------------------------
template <int EPI>
__launch_bounds__(512, 2)
__global__ void gemm256_k(const f16* __restrict__ A, const f16* __restrict__ Bt,
                          void* __restrict__ Cout, int M, int N, int K,
                          const float* __restrict__ bias,
                          const f16* __restrict__ auxh,
                          const float* __restrict__ betap) {
  __shared__ alignas(16) f16 lds[65536];  // [buf0 A|buf0 B|buf1 A|buf1 B] 128KiB
  const int t = threadIdx.x, lane = t & 63, w = t >> 6;
  const int wm = w >> 2, wn = w & 3;
  const int bm = blockIdx.y << 8, bn = blockIdx.x << 8;
  const int l5 = lane & 31, hi = lane >> 5;
  const int NT = K >> 6;
  const int lrow = lane >> 3;                   // row within an 8-row issue
  const int lco  = ((lane & 7) ^ lrow) << 3;    // swizzled source chunk (f16)

  const f16* Agl = A  + (size_t)(bm + lrow) * K + lco;
  const f16* Bgl = Bt + (size_t)(bn + lrow) * K + lco;
  const int aw = w << 3;    // per-wave A staging base row
  const int bw = w << 4;    // per-wave B staging base row

  f32x16 acc[4][2] = {};    // [mi 32-row block][ni 32-col block]
  f16x8 bf[2][4];           // [ni][ks]

  auto stA = [&](int tile, int half) {  // half0: rows {aw, 128+aw}; half1: +64
    const int d = (tile & 1) << 15;
    const int k0 = tile << 6;
    const int r0 = aw + (half << 6);
    gload_lds16(Agl + (size_t)r0 * K + k0, (void*)&lds[d + r0 * 64]);
    gload_lds16(Agl + (size_t)(r0 + 128) * K + k0, (void*)&lds[d + (r0 + 128) * 64]);
  };
  auto stB = [&](int tile, int half) {  // half0: rows {bw, bw+8}; half1: +128
    const int d = ((tile & 1) << 15) + 16384;
    const int k0 = tile << 6;
    const int r0 = bw + (half << 7);
    gload_lds16(Bgl + (size_t)r0 * K + k0, (void*)&lds[d + r0 * 64]);
    gload_lds16(Bgl + (size_t)(r0 + 8) * K + k0, (void*)&lds[d + (r0 + 8) * 64]);
  };
  // A frag for 32x32x16: row = wm*128 + mi*32 + (lane&31), k = ks*16 + hi*8
  auto ldA = [&](int d, int mi, int ks) {
    const int r = (wm << 7) + (mi << 5) + l5;
    return *(const f16x8*)&lds[(d << 15) + r * 64 + ((((ks << 1) + hi) ^ (r & 7)) << 3)];
  };
  auto ldB = [&](int d, int ni, int ks) {
    const int r = (wn << 6) + (ni << 5) + l5;
    return *(const f16x8*)&lds[(d << 15) + 16384 + r * 64 + ((((ks << 1) + hi) ^ (r & 7)) << 3)];
  };

  // prologue: tile0 fully + tile1 minus A-half1 (14 loads; first 8 = tile0)
  stB(0, 0); stB(0, 1); stA(0, 0); stA(0, 1);
  stB(1, 0); stB(1, 1); stA(1, 0);
  asm volatile("s_waitcnt vmcnt(6)" ::: "memory");
  __builtin_amdgcn_s_barrier();

  for (int tt = 0; tt < NT; tt += 2) {
    const bool pf = (tt + 2 < NT);
#pragma unroll
    for (int hf = 0; hf < 2; ++hf) {  // hf0: tile tt (buf0); hf1: tile tt+1 (buf1)
#pragma unroll
      for (int ph = 0; ph < 4; ++ph) {  // ph = mi quadrant (32 rows)
        f16x8 af0 = ldA(hf, ph, 0), af1 = ldA(hf, ph, 1);
        f16x8 af2 = ldA(hf, ph, 2), af3 = ldA(hf, ph, 3);
        if (ph == 0) {
#pragma unroll
          for (int ni = 0; ni < 2; ++ni)
#pragma unroll
            for (int ks = 0; ks < 4; ++ks) bf[ni][ks] = ldB(hf, ni, ks);
        }
        if (hf == 0) {
          if (ph == 0) stA(tt + 1, 1);
          else if (ph == 1) { if (pf) stB(tt + 2, 0); }
          else if (ph == 2) { if (pf) stB(tt + 2, 1); }
          else              { if (pf) stA(tt + 2, 0); }
        } else {
          if (ph == 0)      { if (pf) stA(tt + 2, 1); }
          else if (ph == 1) { if (pf) stB(tt + 3, 0); }
          else if (ph == 2) { if (pf) stB(tt + 3, 1); }
          else              { if (pf) stA(tt + 3, 0); }
        }
        __builtin_amdgcn_s_barrier();
        __builtin_amdgcn_s_setprio(1);
#pragma unroll
        for (int ni = 0; ni < 2; ++ni) {
          acc[ph][ni] = MFMA_32x32x16(af0, bf[ni][0], acc[ph][ni]);
          acc[ph][ni] = MFMA_32x32x16(af1, bf[ni][1], acc[ph][ni]);
          acc[ph][ni] = MFMA_32x32x16(af2, bf[ni][2], acc[ph][ni]);
          acc[ph][ni] = MFMA_32x32x16(af3, bf[ni][3], acc[ph][ni]);
        }
        __builtin_amdgcn_s_setprio(0);
        if (ph == 3) {
          if (hf == 0) {
            if (pf) asm volatile("s_waitcnt vmcnt(6)" ::: "memory");
            else    asm volatile("s_waitcnt vmcnt(0)" ::: "memory");
          } else if (pf) {
            asm volatile("s_waitcnt vmcnt(6)" ::: "memory");
          }
        }
        __builtin_amdgcn_s_barrier();
      }
    }
  }

  const float be = (EPI == 3) ? betap[0] : 0.f;
#pragma unroll
  for (int mi = 0; mi < 4; ++mi) {
#pragma unroll
    for (int ni = 0; ni < 2; ++ni) {
#pragma unroll
      for (int r = 0; r < 16; ++r) {
        const int grow = bm + (wm << 7) + (mi << 5) + (r & 3) + ((r >> 2) << 3) + (hi << 2);
        const int gcol = bn + (wn << 6) + (ni << 5) + l5;
        float v = acc[mi][ni][r] + bias[gcol];
        const size_t off = (size_t)grow * N + gcol;
        if (EPI == 2) {
          ((f16*)Cout)[off] = (f16)v;
        } else if (EPI == 3) {
          ((f16*)Cout)[off] = (f16)(v / (1.f + __expf(-be * v)));
        } else {
          ((f16*)Cout)[off] = (f16)(v * (float)auxh[off]);
        }
      }
    }
  }
}

// ---------------------------------------------------------------------------
// 128x128 GEMM (proven 16x16x32), 3 blocks/CU.
// EPI: 0=rope*scale->f16  1=plain->f16  5=+bias,+auxh(f16 residual)->f32
// ---------------------------------------------------------------------------
template <int EPI>
__launch_bounds__(256, 3)
__global__ void gemm_k(const f16* __restrict__ A, const f16* __restrict__ Bt,
                       void* __restrict__ Cout, int M, int N, int K,
                       const float* __restrict__ bias,
                       const float* __restrict__ auxf,
                       const f16* __restrict__ auxh,
                       float scale) {
  __shared__ alignas(16) f16 As[128 * 64];
  __shared__ alignas(16) f16 Bs[128 * 64];
  const int t = threadIdx.x;
  const int lane = t & 63;
  const int w = t >> 6;
  const int wm = w >> 1, wn = w & 1;
  const int bm = blockIdx.y << 7;
  const int bn = blockIdx.x << 7;
  const int lh = lane & 15, lq = lane >> 4;

  f32x4 acc[4][4] = {};

  for (int k0 = 0; k0 < K; k0 += 64) {
    __syncthreads();
#pragma unroll
    for (int i = 0; i < 4; ++i) {
      const int idx = i * 256 + (w << 6) + lane;
      const int row = idx >> 3, c = idx & 7;
      const int cs = (c ^ (row & 7)) << 3;
      gload_lds16(A + (size_t)(bm + row) * K + k0 + cs,
                  &As[(i * 256 + (w << 6)) << 3]);
      gload_lds16(Bt + (size_t)(bn + row) * K + k0 + cs,
                  &Bs[(i * 256 + (w << 6)) << 3]);
    }
    asm volatile("s_waitcnt vmcnt(0)" ::: "memory");
    __syncthreads();
#pragma unroll
    for (int kk = 0; kk < 2; ++kk) {
      f16x8 af[4], bfr[4];
#pragma unroll
      for (int mi = 0; mi < 4; ++mi) {
        const int r = (wm << 6) + (mi << 4) + lh;
        af[mi] = *(const f16x8*)&As[(r << 6) + ((((kk << 2) + lq) ^ (r & 7)) << 3)];
      }
#pragma unroll
      for (int ni = 0; ni < 4; ++ni) {
        const int r = (wn << 6) + (ni << 4) + lh;
        bfr[ni] = *(const f16x8*)&Bs[(r << 6) + ((((kk << 2) + lq) ^ (r & 7)) << 3)];
      }
#pragma unroll
      for (int mi = 0; mi < 4; ++mi)
#pragma unroll
        for (int ni = 0; ni < 4; ++ni)
          acc[mi][ni] = MFMA_16x16x32(af[mi], bfr[ni], acc[mi][ni]);
    }
  }

#pragma unroll
  for (int mi = 0; mi < 4; ++mi) {
#pragma unroll
    for (int ni = 0; ni < 4; ++ni) {
#pragma unroll
      for (int r = 0; r < 4; ++r) {
        const int grow = bm + (wm << 6) + (mi << 4) + (lq << 2) + r;
        const int gcol = bn + (wn << 6) + (ni << 4) + lh;
        float v = acc[mi][ni][r];
        const size_t off = (size_t)grow * N + gcol;
        if (EPI == 0) {
          v *= scale * auxf[((grow & 2047) << 7) + (gcol & 127)];
          ((f16*)Cout)[off] = (f16)v;
        } else if (EPI == 1) {
          ((f16*)Cout)[off] = (f16)v;
        } else {
          ((float*)Cout)[off] = v + bias[gcol] + (float)auxh[off];
        }
      }
    }
  }
}

// ---------------------------------------------------------------------------
// Causal flash attention v3 (round-10 validated): work queue + counted-vmcnt
// pipeline. 384 blocks x 256 thr, 2 blocks/CU. X2 output f16.
// ---------------------------------------------------------------------------
__launch_bounds__(256, 2)
__global__ void attn_k(const f16* __restrict__ Q, const f16* __restrict__ Kb,
                       const f16* __restrict__ Vt, const float* __restrict__ Xres,
                       f16* __restrict__ X2, int* __restrict__ qcnt) {
  constexpr int L = 2048, E = 2048, HD = 128;
  __shared__ alignas(16) f16 Ks[2][64 * 128];
  __shared__ alignas(16) f16 Vs[128 * 64];
  __shared__ alignas(16) f16 Ps[4][32 * 72];
  __shared__ int s_item;

  const int t = threadIdx.x, lane = t & 63, w = t >> 6;
  const int lh = lane & 15, lq = lane >> 4;

  for (;;) {
    if (t == 0) s_item = atomicAdd(qcnt, 1);
    __syncthreads();                 // full drain: vmcnt accounting resets to 0
    const int item = s_item;
    if (item >= 512) return;
    const int bh = item & 31;                 // head-major within a q-band
    const int q0 = (15 - (item >> 5)) << 7;   // heaviest q-tiles first (LPT)
    const int b = bh >> 4, h = bh & 15;
    const int wrow0 = q0 + (w << 5);

    auto issueK = [&](int kv0, int buf) {  // 4 gload_lds -> Ks[buf]
#pragma unroll
      for (int i = 0; i < 4; ++i) {
        const int idx = i * 256 + (w << 6) + lane;
        const int row = idx >> 4, c = idx & 15;
        gload_lds16(Kb + (size_t)(b * L + kv0 + row) * E + h * HD + ((c ^ (row & 7)) << 3),
                    &Ks[buf][(i * 256 + (w << 6)) << 3]);
      }
    };
    auto issueV = [&](int kv0) {           // 4 gload_lds -> Vs
#pragma unroll
      for (int i = 0; i < 4; ++i) {
        const int idx = i * 256 + (w << 6) + lane;
        const int row = idx >> 3, c = idx & 7;
        gload_lds16(Vt + ((size_t)bh * HD + row) * L + kv0 + ((c ^ (row & 7)) << 3),
                    &Vs[(i * 256 + (w << 6)) << 3]);
      }
    };

    f16x8 qf[2][4];
#pragma unroll
    for (int mi = 0; mi < 2; ++mi) {
      const f16* qrow = Q + (size_t)(b * L + wrow0 + (mi << 4) + lh) * E + h * HD;
#pragma unroll
      for (int kq = 0; kq < 4; ++kq)
        qf[mi][kq] = *(const f16x8*)(qrow + (kq << 5) + (lq << 3));
    }
    asm volatile("s_waitcnt vmcnt(0)" ::: "memory");  // qf resident; count = 0

    f32x4 oacc[2][8] = {};
    float mrun[2][4], lrun[2][4];
#pragma unroll
    for (int mi = 0; mi < 2; ++mi)
#pragma unroll
      for (int r = 0; r < 4; ++r) { mrun[mi][r] = -1e30f; lrun[mi][r] = 0.f; }

    const int nt = (q0 + 128) >> 6;
    issueK(0, 0);                                    // outstanding: 4
    for (int it = 0; it < nt; ++it) {
      const int cur = it & 1;
      const int kv0 = it << 6;
      const bool more = (it + 1 < nt);
      issueV(kv0);                                   // outstanding: 8
      if (more) {
        issueK(kv0 + 64, cur ^ 1);                   // outstanding: 12
        asm volatile("s_waitcnt vmcnt(8)" ::: "memory");   // K[cur] retired
      } else {
        asm volatile("s_waitcnt vmcnt(4)" ::: "memory");
      }
      __builtin_amdgcn_s_barrier();                  // Ks[cur] visible

      const bool active = (kv0 <= wrow0 + 31);
      if (active) {
        f32x4 sacc[2][4] = {};
#pragma unroll
        for (int kq = 0; kq < 4; ++kq) {
          f16x8 kf[4];
#pragma unroll
          for (int ni = 0; ni < 4; ++ni) {
            const int r = (ni << 4) + lh;
            kf[ni] = *(const f16x8*)&Ks[cur][(r << 7) + ((((kq << 2) + lq) ^ (r & 7)) << 3)];
          }
#pragma unroll
          for (int mi = 0; mi < 2; ++mi)
#pragma unroll
            for (int ni = 0; ni < 4; ++ni)
              sacc[mi][ni] = MFMA_16x16x32(qf[mi][kq], kf[ni], sacc[mi][ni]);
        }
        if (kv0 + 63 > wrow0) {
#pragma unroll
          for (int mi = 0; mi < 2; ++mi)
#pragma unroll
            for (int ni = 0; ni < 4; ++ni)
#pragma unroll
              for (int r = 0; r < 4; ++r) {
                const int qr = wrow0 + (mi << 4) + (lq << 2) + r;
                const int kv = kv0 + (ni << 4) + lh;
                if (kv > qr) sacc[mi][ni][r] = -1e30f;
              }
        }
        float scl[2][4], rsum[2][4];
#pragma unroll
        for (int mi = 0; mi < 2; ++mi)
#pragma unroll
          for (int r = 0; r < 4; ++r) {
            float v = fmaxf(fmaxf(sacc[mi][0][r], sacc[mi][1][r]),
                            fmaxf(sacc[mi][2][r], sacc[mi][3][r]));
            v = fmaxf(v, __shfl_xor(v, 1));
            v = fmaxf(v, __shfl_xor(v, 2));
            v = fmaxf(v, __shfl_xor(v, 4));
            v = fmaxf(v, __shfl_xor(v, 8));
            const float mnew = fmaxf(mrun[mi][r], v);
            scl[mi][r] = __expf(mrun[mi][r] - mnew);
            mrun[mi][r] = mnew;
            rsum[mi][r] = 0.f;
          }
#pragma unroll
        for (int mi = 0; mi < 2; ++mi)
#pragma unroll
          for (int ni = 0; ni < 4; ++ni)
#pragma unroll
            for (int r = 0; r < 4; ++r) {
              const float p = __expf(sacc[mi][ni][r] - mrun[mi][r]);
              rsum[mi][r] += p;
              Ps[w][((mi << 4) + (lq << 2) + r) * 72 + (ni << 4) + lh] = (f16)p;
            }
#pragma unroll
        for (int mi = 0; mi < 2; ++mi)
#pragma unroll
          for (int r = 0; r < 4; ++r) {
            float s = rsum[mi][r];
            s += __shfl_xor(s, 1);
            s += __shfl_xor(s, 2);
            s += __shfl_xor(s, 4);
            s += __shfl_xor(s, 8);
            lrun[mi][r] = lrun[mi][r] * scl[mi][r] + s;
          }
#pragma unroll
        for (int mi = 0; mi < 2; ++mi)
#pragma unroll
          for (int nd = 0; nd < 8; ++nd)
#pragma unroll
            for (int r = 0; r < 4; ++r) oacc[mi][nd][r] *= scl[mi][r];
      }

      if (more) asm volatile("s_waitcnt vmcnt(4)" ::: "memory");  // V retired
      else      asm volatile("s_waitcnt vmcnt(0)" ::: "memory");
      __builtin_amdgcn_s_barrier();                  // Vs visible

      if (active) {
#pragma unroll
        for (int kp = 0; kp < 2; ++kp) {
          f16x8 pf[2];
#pragma unroll
          for (int mi = 0; mi < 2; ++mi)
            pf[mi] = *(const f16x8*)&Ps[w][((mi << 4) + lh) * 72 + (kp << 5) + (lq << 3)];
#pragma unroll
          for (int nd = 0; nd < 8; ++nd) {
            const int r = (nd << 4) + lh;
            const f16x8 vf = *(const f16x8*)&Vs[(r << 6) + ((((kp << 2) + lq) ^ (r & 7)) << 3)];
#pragma unroll
            for (int mi = 0; mi < 2; ++mi)
              oacc[mi][nd] = MFMA_16x16x32(pf[mi], vf, oacc[mi][nd]);
          }
        }
      }
      asm volatile("" ::: "memory");
      __builtin_amdgcn_s_barrier();                  // readers done before overwrite
    }
#pragma unroll
    for (int mi = 0; mi < 2; ++mi)
#pragma unroll
      for (int nd = 0; nd < 8; ++nd)
#pragma unroll
        for (int r = 0; r < 4; ++r) {
          const int qr = wrow0 + (mi << 4) + (lq << 2) + r;
          const size_t off = (size_t)(b * L + qr) * E + h * HD + (nd << 4) + lh;
          X2[off] = (f16)(oacc[mi][nd][r] / lrun[mi][r] + Xres[off]);
        }
  }
}

// ---------------------------------------------------------------------------
extern "C" void kernel_launch(void* const* d_in, const int* in_sizes, int n_in,
                              void* d_out, int out_size, void* d_ws, size_t ws_size,
                              hipStream_t stream) {
  const float* x    = (const float*)d_in[0];
  const float* g    = (const float*)d_in[1];
  const float* wq   = (const float*)d_in[2];
  const float* wk   = (const float*)d_in[3];
  const float* wv   = (const float*)d_in[4];
  const float* w1   = (const float*)d_in[5];
  const float* b1   = (const float*)d_in[6];
  const float* wgp  = (const float*)d_in[7];
  const float* bg   = (const float*)d_in[8];
  const float* wl   = (const float*)d_in[9];
  const float* bl   = (const float*)d_in[10];
  const float* beta = (const float*)d_in[11];
  const float* w2   = (const float*)d_in[12];
  const float* b2   = (const float*)d_in[13];

  constexpr size_t MB = 1ull << 20;
  char* ws = (char*)d_ws;
  // ws layout (MB):
  //  0..32  wT (QKV convTs use 0..24; qcnt@31 untouched until post-attn convTs)
  //  32..33 Dt rope table
  //  33..49 hbuf
  //  49..65 qbuf   | a1 (49..81) after attention
  //  65..81 kbuf   |
  //  81..97 vbuf   | sbuf (81..113) after attention
  //  97..113 vtb   |
  //  113..129 x2h (f16 residual)
  //  145..177 act
  f16*   wT   = (f16*)(ws + 0 * MB);
  int*   qcnt = (int*)(ws + 31 * MB);
  float* Dt   = (float*)(ws + 32 * MB);
  f16*   hbuf = (f16*)(ws + 33 * MB);
  f16*   qbuf = (f16*)(ws + 49 * MB);
  f16*   kbuf = (f16*)(ws + 65 * MB);
  f16*   vbuf = (f16*)(ws + 81 * MB);
  f16*   vtb  = (f16*)(ws + 97 * MB);
  f16*   x2h  = (f16*)(ws + 113 * MB);
  f16*   a1   = (f16*)(ws + 49 * MB);     // reuse q+k after attention
  f16*   sbuf = (f16*)(ws + 81 * MB);     // reuse v+vt after attention
  f16*   act  = (f16*)(ws + 145 * MB);
  (void)ws_size; (void)n_in; (void)in_sizes; (void)out_size;

  const dim3 blk(256);
  const float qscale = 0.08838834764831845f;  // 1/sqrt(128)

  rope_tab_k<<<2048, 128, 0, stream>>>(Dt);
  rmsnorm_k<<<4096, blk, 0, stream>>>(x, g, hbuf);
  hipMemsetAsync(qcnt, 0, 4, stream);

  // QKV on 128^2 (16x16x32, proven)
  f16* wqT = wT;
  f16* wkT = wT + (size_t)2048 * 2048;
  f16* wvT = wT + (size_t)4096 * 2048;
  convT_k<<<dim3(64, 64), blk, 0, stream>>>(wq, wqT, 2048, 2048);
  convT_k<<<dim3(64, 64), blk, 0, stream>>>(wk, wkT, 2048, 2048);
  convT_k<<<dim3(64, 64), blk, 0, stream>>>(wv, wvT, 2048, 2048);
  gemm_k<0><<<dim3(16, 32), blk, 0, stream>>>(hbuf, wqT, qbuf, 4096, 2048, 2048,
                                              nullptr, Dt, nullptr, qscale);
  gemm_k<0><<<dim3(16, 32), blk, 0, stream>>>(hbuf, wkT, kbuf, 4096, 2048, 2048,
                                              nullptr, Dt, nullptr, 1.0f);
  gemm_k<1><<<dim3(16, 32), blk, 0, stream>>>(hbuf, wvT, vbuf, 4096, 2048, 2048,
                                              nullptr, nullptr, nullptr, 1.0f);
  vtrans_k<<<dim3(64, 4, 32), blk, 0, stream>>>(vbuf, vtb);

  attn_k<<<384, blk, 0, stream>>>(qbuf, kbuf, vtb, x, x2h, qcnt);

  rmsnorm_h_k<<<4096, blk, 0, stream>>>(x2h, g, hbuf);

  // MLP on 256^2 8-phase, MFMA 32x32x16
  convT_k<<<dim3(128, 64), blk, 0, stream>>>(w1, wT, 2048, 4096);
  gemm256_k<2><<<dim3(16, 16), 512, 0, stream>>>(hbuf, wT, a1, 4096, 4096, 2048,
                                                 b1, nullptr, nullptr);
  convT_k<<<dim3(128, 128), blk, 0, stream>>>(wgp, wT, 4096, 4096);
  gemm256_k<3><<<dim3(16, 16), 512, 0, stream>>>(a1, wT, sbuf, 4096, 4096, 4096,
                                                 bg, nullptr, beta);
  convT_k<<<dim3(128, 128), blk, 0, stream>>>(wl, wT, 4096, 4096);
  gemm256_k<4><<<dim3(16, 16), 512, 0, stream>>>(a1, wT, act, 4096, 4096, 4096,
                                                 bl, sbuf, nullptr);
  // out = act @ w2 + b2 + x2  (128^2, 16x16x32)
  convT_k<<<dim3(64, 128), blk, 0, stream>>>(w2, wT, 4096, 2048);
  gemm_k<5><<<dim3(16, 32), blk, 0, stream>>>(act, wT, (float*)d_out, 4096, 2048, 4096,
                                              b2, nullptr, x2h, 1.0f);
}

// Round 13
// 723.528 us; speedup vs baseline: 1.1031x; 1.1031x over previous
//
#include <hip/hip_runtime.h>
#include <cstdint>
#include <math.h>

// ---------------------------------------------------------------------------
// LlamaSelfAttentionBlock: rmsnorm -> QKV (rope-diag) -> causal attn -> +res
//                          -> rmsnorm -> w1+b1 -> silu(beta*gate)*lin -> w2+b2 -> +res
// fp16 MFMA (16x16x32), f32 accumulate. B=2,L=2048,E=2048,H=16,hd=128,F=4096.
// Round 13: gemm256 reverted to 16x16x32 round-4 exact (32x32 regressed:
// 4-way bank conflict, rows stride 128B all land on bank 0). QKV fused into
// ONE N=6144 gemm_k dispatch (1536 blocks = exactly 2 full rounds @3/CU;
// 3x512-block dispatches only filled 2/3 of the machine each).
// attn: round-10 counted-vmcnt pipeline. x2 residual f16.
// ---------------------------------------------------------------------------

typedef _Float16 f16;
typedef _Float16 f16x8 __attribute__((ext_vector_type(8)));
typedef _Float16 f16x4 __attribute__((ext_vector_type(4)));
typedef float    f32x4 __attribute__((ext_vector_type(4)));

#define MFMA_16x16x32(a, b, c) __builtin_amdgcn_mfma_f32_16x16x32_f16(a, b, c, 0, 0, 0)

__device__ __forceinline__ void gload_lds16(const void* g, void* lds) {
  __builtin_amdgcn_global_load_lds(
      (__attribute__((address_space(1))) void*)(uintptr_t)g,
      (__attribute__((address_space(3))) void*)(unsigned)(uintptr_t)lds,
      16, 0, 0);
}

// ---------------------------------------------------------------------------
// f32 [K][N] -> fp16 [N][K] transpose+convert (32x32 LDS tile)
// ---------------------------------------------------------------------------
__global__ void convT_k(const float* __restrict__ W, f16* __restrict__ Wt,
                        int K, int N) {
  __shared__ float tile[32][33];
  const int n0 = blockIdx.x << 5, k0 = blockIdx.y << 5;
  const int t = threadIdx.x;
  const int r = t >> 3, c4 = (t & 7) << 2;
  const f32x4 v = *(const f32x4*)(W + (size_t)(k0 + r) * N + n0 + c4);
  tile[r][c4 + 0] = v[0]; tile[r][c4 + 1] = v[1];
  tile[r][c4 + 2] = v[2]; tile[r][c4 + 3] = v[3];
  __syncthreads();
  f16x4 o;
  o[0] = (f16)tile[c4 + 0][r]; o[1] = (f16)tile[c4 + 1][r];
  o[2] = (f16)tile[c4 + 2][r]; o[3] = (f16)tile[c4 + 3][r];
  *(f16x4*)(Wt + (size_t)(n0 + r) * K + k0 + c4) = o;
}

// ---------------------------------------------------------------------------
// rope diag table: D[l][d] = cos(l * 10000^(-2*(d/2)/128)), f32 [2048][128]
// ---------------------------------------------------------------------------
__global__ void rope_tab_k(float* __restrict__ Dt) {
  const int l = blockIdx.x, d = threadIdx.x;
  const float th = __expf(-0.0719557841f * (float)(d & ~1));
  Dt[(l << 7) + d] = cosf((float)l * th);
}

// ---------------------------------------------------------------------------
// RMSNorm (f32 input): one block (256 thr) per row of 2048
// ---------------------------------------------------------------------------
__global__ void rmsnorm_k(const float* __restrict__ X, const float* __restrict__ G,
                          f16* __restrict__ H) {
  __shared__ float red[4];
  const int row = blockIdx.x, t = threadIdx.x;
  const float* xp = X + ((size_t)row << 11) + (t << 3);
  const f32x4 v0 = *(const f32x4*)xp;
  const f32x4 v1 = *(const f32x4*)(xp + 4);
  float ss = v0[0]*v0[0] + v0[1]*v0[1] + v0[2]*v0[2] + v0[3]*v0[3]
           + v1[0]*v1[0] + v1[1]*v1[1] + v1[2]*v1[2] + v1[3]*v1[3];
#pragma unroll
  for (int m = 1; m < 64; m <<= 1) ss += __shfl_xor(ss, m);
  if ((t & 63) == 0) red[t >> 6] = ss;
  __syncthreads();
  const float tot = red[0] + red[1] + red[2] + red[3];
  const float rs = rsqrtf(tot * (1.f / 2048.f) + 1e-6f);
  const float* gp = G + (t << 3);
  const f32x4 g0 = *(const f32x4*)gp, g1 = *(const f32x4*)(gp + 4);
  f16x8 o;
  o[0] = (f16)(v0[0]*rs*g0[0]); o[1] = (f16)(v0[1]*rs*g0[1]);
  o[2] = (f16)(v0[2]*rs*g0[2]); o[3] = (f16)(v0[3]*rs*g0[3]);
  o[4] = (f16)(v1[0]*rs*g1[0]); o[5] = (f16)(v1[1]*rs*g1[1]);
  o[6] = (f16)(v1[2]*rs*g1[2]); o[7] = (f16)(v1[3]*rs*g1[3]);
  *(f16x8*)(H + ((size_t)row << 11) + (t << 3)) = o;
}

// ---------------------------------------------------------------------------
// RMSNorm (f16 input) — for the f16 x2 residual buffer
// ---------------------------------------------------------------------------
__global__ void rmsnorm_h_k(const f16* __restrict__ X, const float* __restrict__ G,
                            f16* __restrict__ H) {
  __shared__ float red[4];
  const int row = blockIdx.x, t = threadIdx.x;
  const f16x8 v = *(const f16x8*)(X + ((size_t)row << 11) + (t << 3));
  float f[8];
#pragma unroll
  for (int i = 0; i < 8; ++i) f[i] = (float)v[i];
  float ss = 0.f;
#pragma unroll
  for (int i = 0; i < 8; ++i) ss += f[i] * f[i];
#pragma unroll
  for (int m = 1; m < 64; m <<= 1) ss += __shfl_xor(ss, m);
  if ((t & 63) == 0) red[t >> 6] = ss;
  __syncthreads();
  const float tot = red[0] + red[1] + red[2] + red[3];
  const float rs = rsqrtf(tot * (1.f / 2048.f) + 1e-6f);
  const float* gp = G + (t << 3);
  const f32x4 g0 = *(const f32x4*)gp, g1 = *(const f32x4*)(gp + 4);
  f16x8 o;
#pragma unroll
  for (int i = 0; i < 4; ++i) o[i] = (f16)(f[i] * rs * g0[i]);
#pragma unroll
  for (int i = 0; i < 4; ++i) o[4 + i] = (f16)(f[4 + i] * rs * g1[i]);
  *(f16x8*)(H + ((size_t)row << 11) + (t << 3)) = o;
}

// ---------------------------------------------------------------------------
// per-head V transpose: V [B*L][E] -> Vt [B*H][128][2048]  (fp16)
// ---------------------------------------------------------------------------
__global__ void vtrans_k(const f16* __restrict__ V, f16* __restrict__ Vt) {
  __shared__ f16 tile[32][36];
  const int l0 = blockIdx.x << 5, d0 = blockIdx.y << 5, bh = blockIdx.z;
  const int b = bh >> 4, h = bh & 15;
  const int t = threadIdx.x;
  const int r = t >> 3, c4 = (t & 7) << 2;
  const f16x4 v = *(const f16x4*)(V + (size_t)((b << 11) + l0 + r) * 2048 + (h << 7) + d0 + c4);
  tile[r][c4 + 0] = v[0]; tile[r][c4 + 1] = v[1];
  tile[r][c4 + 2] = v[2]; tile[r][c4 + 3] = v[3];
  __syncthreads();
  f16x4 o;
  o[0] = tile[c4 + 0][r]; o[1] = tile[c4 + 1][r];
  o[2] = tile[c4 + 2][r]; o[3] = tile[c4 + 3][r];
  *(f16x4*)(Vt + (size_t)((bh << 7) + d0 + r) * 2048 + l0 + c4) = o;
}

// ---------------------------------------------------------------------------
// 256x256-tile 8-phase fp16 GEMM — ROUND-4 EXACT (875 TF, 0 bank conflicts).
// EPI: 2=+bias  3=+bias,silu(beta)  4=+bias,*auxh
// ---------------------------------------------------------------------------
template <int EPI>
__launch_bounds__(512, 2)
__global__ void gemm256_k(const f16* __restrict__ A, const f16* __restrict__ Bt,
                          void* __restrict__ Cout, int M, int N, int K,
                          const float* __restrict__ bias,
                          const f16* __restrict__ auxh,
                          const float* __restrict__ betap) {
  __shared__ alignas(16) f16 lds[65536];  // [buf0 A|buf0 B|buf1 A|buf1 B] 128KiB
  const int t = threadIdx.x, lane = t & 63, w = t >> 6;
  const int wm = w >> 2, wn = w & 3;
  const int bm = blockIdx.y << 8, bn = blockIdx.x << 8;
  const int lh = lane & 15, lq = lane >> 4;
  const int NT = K >> 6;
  const int lrow = lane >> 3;                   // row within an 8-row issue
  const int lco  = ((lane & 7) ^ lrow) << 3;    // swizzled source chunk (f16)

  const f16* Agl = A  + (size_t)(bm + lrow) * K + lco;
  const f16* Bgl = Bt + (size_t)(bn + lrow) * K + lco;
  const int aw = w << 3;    // per-wave A staging base row
  const int bw = w << 4;    // per-wave B staging base row

  f32x4 acc[8][4] = {};
  f16x8 bf[4][2];

  auto stA = [&](int tile, int half) {  // half0: rows {aw, 128+aw}; half1: +64
    const int d = (tile & 1) << 15;
    const int k0 = tile << 6;
    const int r0 = aw + (half << 6);
    gload_lds16(Agl + (size_t)r0 * K + k0, (void*)&lds[d + r0 * 64]);
    gload_lds16(Agl + (size_t)(r0 + 128) * K + k0, (void*)&lds[d + (r0 + 128) * 64]);
  };
  auto stB = [&](int tile, int half) {  // half0: rows {bw, bw+8}; half1: +128
    const int d = ((tile & 1) << 15) + 16384;
    const int k0 = tile << 6;
    const int r0 = bw + (half << 7);
    gload_lds16(Bgl + (size_t)r0 * K + k0, (void*)&lds[d + r0 * 64]);
    gload_lds16(Bgl + (size_t)(r0 + 8) * K + k0, (void*)&lds[d + (r0 + 8) * 64]);
  };
  auto ldA = [&](int d, int mi, int kk) {
    const int r = (wm << 7) + (mi << 4) + lh;
    return *(const f16x8*)&lds[(d << 15) + r * 64 + ((((kk << 2) + lq) ^ (lh & 7)) << 3)];
  };
  auto ldB = [&](int d, int ni, int kk) {
    const int r = (wn << 6) + (ni << 4) + lh;
    return *(const f16x8*)&lds[(d << 15) + 16384 + r * 64 + ((((kk << 2) + lq) ^ (lh & 7)) << 3)];
  };

  // prologue: tile0 fully + tile1 minus A-half1 (14 loads; first 8 = tile0)
  stB(0, 0); stB(0, 1); stA(0, 0); stA(0, 1);
  stB(1, 0); stB(1, 1); stA(1, 0);
  asm volatile("s_waitcnt vmcnt(6)" ::: "memory");
  __builtin_amdgcn_s_barrier();

  for (int tt = 0; tt < NT; tt += 2) {
    const bool pf = (tt + 2 < NT);
#pragma unroll
    for (int hf = 0; hf < 2; ++hf) {  // hf0: tile tt (buf0); hf1: tile tt+1 (buf1)
#pragma unroll
      for (int ph = 0; ph < 4; ++ph) {
        f16x8 a0k0 = ldA(hf, 2 * ph, 0),     a0k1 = ldA(hf, 2 * ph, 1);
        f16x8 a1k0 = ldA(hf, 2 * ph + 1, 0), a1k1 = ldA(hf, 2 * ph + 1, 1);
        if (ph == 0) {
#pragma unroll
          for (int ni = 0; ni < 4; ++ni) {
            bf[ni][0] = ldB(hf, ni, 0); bf[ni][1] = ldB(hf, ni, 1);
          }
        }
        if (hf == 0) {
          if (ph == 0) stA(tt + 1, 1);
          else if (ph == 1) { if (pf) stB(tt + 2, 0); }
          else if (ph == 2) { if (pf) stB(tt + 2, 1); }
          else              { if (pf) stA(tt + 2, 0); }
        } else {
          if (ph == 0)      { if (pf) stA(tt + 2, 1); }
          else if (ph == 1) { if (pf) stB(tt + 3, 0); }
          else if (ph == 2) { if (pf) stB(tt + 3, 1); }
          else              { if (pf) stA(tt + 3, 0); }
        }
        __builtin_amdgcn_s_barrier();
        __builtin_amdgcn_s_setprio(1);
#pragma unroll
        for (int ni = 0; ni < 4; ++ni) {
          acc[2 * ph][ni]     = MFMA_16x16x32(a0k0, bf[ni][0], acc[2 * ph][ni]);
          acc[2 * ph][ni]     = MFMA_16x16x32(a0k1, bf[ni][1], acc[2 * ph][ni]);
          acc[2 * ph + 1][ni] = MFMA_16x16x32(a1k0, bf[ni][0], acc[2 * ph + 1][ni]);
          acc[2 * ph + 1][ni] = MFMA_16x16x32(a1k1, bf[ni][1], acc[2 * ph + 1][ni]);
        }
        __builtin_amdgcn_s_setprio(0);
        if (ph == 3) {
          if (hf == 0) {
            if (pf) asm volatile("s_waitcnt vmcnt(6)" ::: "memory");
            else    asm volatile("s_waitcnt vmcnt(0)" ::: "memory");
          } else if (pf) {
            asm volatile("s_waitcnt vmcnt(6)" ::: "memory");
          }
        }
        __builtin_amdgcn_s_barrier();
      }
    }
  }

  const float be = (EPI == 3) ? betap[0] : 0.f;
#pragma unroll
  for (int mi = 0; mi < 8; ++mi) {
#pragma unroll
    for (int ni = 0; ni < 4; ++ni) {
#pragma unroll
      for (int r = 0; r < 4; ++r) {
        const int grow = bm + (wm << 7) + (mi << 4) + (lq << 2) + r;
        const int gcol = bn + (wn << 6) + (ni << 4) + lh;
        float v = acc[mi][ni][r] + bias[gcol];
        const size_t off = (size_t)grow * N + gcol;
        if (EPI == 2) {
          ((f16*)Cout)[off] = (f16)v;
        } else if (EPI == 3) {
          ((f16*)Cout)[off] = (f16)(v / (1.f + __expf(-be * v)));
        } else {
          ((f16*)Cout)[off] = (f16)(v * (float)auxh[off]);
        }
      }
    }
  }
}

// ---------------------------------------------------------------------------
// 128x128 GEMM (proven 16x16x32), 3 blocks/CU.
// EPI: 1=plain->f16  5=+bias,+auxh(f16 residual)->f32
//      6=fused QKV: seg=gcol>>11 (0=q rope*scale, 1=k rope, 2=v), dest
//      segments 2048-wide at qkv base + seg*8388608.
// ---------------------------------------------------------------------------
template <int EPI>
__launch_bounds__(256, 3)
__global__ void gemm_k(const f16* __restrict__ A, const f16* __restrict__ Bt,
                       void* __restrict__ Cout, int M, int N, int K,
                       const float* __restrict__ bias,
                       const float* __restrict__ auxf,
                       const f16* __restrict__ auxh,
                       float scale) {
  __shared__ alignas(16) f16 As[128 * 64];
  __shared__ alignas(16) f16 Bs[128 * 64];
  const int t = threadIdx.x;
  const int lane = t & 63;
  const int w = t >> 6;
  const int wm = w >> 1, wn = w & 1;
  const int bm = blockIdx.y << 7;
  const int bn = blockIdx.x << 7;
  const int lh = lane & 15, lq = lane >> 4;

  f32x4 acc[4][4] = {};

  for (int k0 = 0; k0 < K; k0 += 64) {
    __syncthreads();
#pragma unroll
    for (int i = 0; i < 4; ++i) {
      const int idx = i * 256 + (w << 6) + lane;
      const int row = idx >> 3, c = idx & 7;
      const int cs = (c ^ (row & 7)) << 3;
      gload_lds16(A + (size_t)(bm + row) * K + k0 + cs,
                  &As[(i * 256 + (w << 6)) << 3]);
      gload_lds16(Bt + (size_t)(bn + row) * K + k0 + cs,
                  &Bs[(i * 256 + (w << 6)) << 3]);
    }
    asm volatile("s_waitcnt vmcnt(0)" ::: "memory");
    __syncthreads();
#pragma unroll
    for (int kk = 0; kk < 2; ++kk) {
      f16x8 af[4], bfr[4];
#pragma unroll
      for (int mi = 0; mi < 4; ++mi) {
        const int r = (wm << 6) + (mi << 4) + lh;
        af[mi] = *(const f16x8*)&As[(r << 6) + ((((kk << 2) + lq) ^ (r & 7)) << 3)];
      }
#pragma unroll
      for (int ni = 0; ni < 4; ++ni) {
        const int r = (wn << 6) + (ni << 4) + lh;
        bfr[ni] = *(const f16x8*)&Bs[(r << 6) + ((((kk << 2) + lq) ^ (r & 7)) << 3)];
      }
#pragma unroll
      for (int mi = 0; mi < 4; ++mi)
#pragma unroll
        for (int ni = 0; ni < 4; ++ni)
          acc[mi][ni] = MFMA_16x16x32(af[mi], bfr[ni], acc[mi][ni]);
    }
  }

#pragma unroll
  for (int mi = 0; mi < 4; ++mi) {
#pragma unroll
    for (int ni = 0; ni < 4; ++ni) {
#pragma unroll
      for (int r = 0; r < 4; ++r) {
        const int grow = bm + (wm << 6) + (mi << 4) + (lq << 2) + r;
        const int gcol = bn + (wn << 6) + (ni << 4) + lh;
        float v = acc[mi][ni][r];
        if (EPI == 6) {
          const int seg = gcol >> 11, c = gcol & 2047;
          if (seg < 2) {
            const float f = auxf[((grow & 2047) << 7) + (c & 127)];
            v *= (seg == 0) ? scale * f : f;
          }
          ((f16*)Cout)[(size_t)seg * 8388608 + ((size_t)grow << 11) + c] = (f16)v;
        } else if (EPI == 1) {
          ((f16*)Cout)[(size_t)grow * N + gcol] = (f16)v;
        } else {
          ((float*)Cout)[(size_t)grow * N + gcol] = v + bias[gcol] + (float)auxh[(size_t)grow * N + gcol];
        }
      }
    }
  }
}

// ---------------------------------------------------------------------------
// Causal flash attention v3 (round-10 validated): work queue + counted-vmcnt
// pipeline. 384 blocks x 256 thr, 2 blocks/CU. X2 output f16.
// ---------------------------------------------------------------------------
__launch_bounds__(256, 2)
__global__ void attn_k(const f16* __restrict__ Q, const f16* __restrict__ Kb,
                       const f16* __restrict__ Vt, const float* __restrict__ Xres,
                       f16* __restrict__ X2, int* __restrict__ qcnt) {
  constexpr int L = 2048, E = 2048, HD = 128;
  __shared__ alignas(16) f16 Ks[2][64 * 128];
  __shared__ alignas(16) f16 Vs[128 * 64];
  __shared__ alignas(16) f16 Ps[4][32 * 72];
  __shared__ int s_item;

  const int t = threadIdx.x, lane = t & 63, w = t >> 6;
  const int lh = lane & 15, lq = lane >> 4;

  for (;;) {
    if (t == 0) s_item = atomicAdd(qcnt, 1);
    __syncthreads();                 // full drain: vmcnt accounting resets to 0
    const int item = s_item;
    if (item >= 512) return;
    const int bh = item & 31;                 // head-major within a q-band
    const int q0 = (15 - (item >> 5)) << 7;   // heaviest q-tiles first (LPT)
    const int b = bh >> 4, h = bh & 15;
    const int wrow0 = q0 + (w << 5);

    auto issueK = [&](int kv0, int buf) {  // 4 gload_lds -> Ks[buf]
#pragma unroll
      for (int i = 0; i < 4; ++i) {
        const int idx = i * 256 + (w << 6) + lane;
        const int row = idx >> 4, c = idx & 15;
        gload_lds16(Kb + (size_t)(b * L + kv0 + row) * E + h * HD + ((c ^ (row & 7)) << 3),
                    &Ks[buf][(i * 256 + (w << 6)) << 3]);
      }
    };
    auto issueV = [&](int kv0) {           // 4 gload_lds -> Vs
#pragma unroll
      for (int i = 0; i < 4; ++i) {
        const int idx = i * 256 + (w << 6) + lane;
        const int row = idx >> 3, c = idx & 7;
        gload_lds16(Vt + ((size_t)bh * HD + row) * L + kv0 + ((c ^ (row & 7)) << 3),
                    &Vs[(i * 256 + (w << 6)) << 3]);
      }
    };

    f16x8 qf[2][4];
#pragma unroll
    for (int mi = 0; mi < 2; ++mi) {
      const f16* qrow = Q + (size_t)(b * L + wrow0 + (mi << 4) + lh) * E + h * HD;
#pragma unroll
      for (int kq = 0; kq < 4; ++kq)
        qf[mi][kq] = *(const f16x8*)(qrow + (kq << 5) + (lq << 3));
    }
    asm volatile("s_waitcnt vmcnt(0)" ::: "memory");  // qf resident; count = 0

    f32x4 oacc[2][8] = {};
    float mrun[2][4], lrun[2][4];
#pragma unroll
    for (int mi = 0; mi < 2; ++mi)
#pragma unroll
      for (int r = 0; r < 4; ++r) { mrun[mi][r] = -1e30f; lrun[mi][r] = 0.f; }

    const int nt = (q0 + 128) >> 6;
    issueK(0, 0);                                    // outstanding: 4
    for (int it = 0; it < nt; ++it) {
      const int cur = it & 1;
      const int kv0 = it << 6;
      const bool more = (it + 1 < nt);
      issueV(kv0);                                   // outstanding: 8
      if (more) {
        issueK(kv0 + 64, cur ^ 1);                   // outstanding: 12
        asm volatile("s_waitcnt vmcnt(8)" ::: "memory");   // K[cur] retired
      } else {
        asm volatile("s_waitcnt vmcnt(4)" ::: "memory");
      }
      __builtin_amdgcn_s_barrier();                  // Ks[cur] visible

      const bool active = (kv0 <= wrow0 + 31);
      if (active) {
        f32x4 sacc[2][4] = {};
#pragma unroll
        for (int kq = 0; kq < 4; ++kq) {
          f16x8 kf[4];
#pragma unroll
          for (int ni = 0; ni < 4; ++ni) {
            const int r = (ni << 4) + lh;
            kf[ni] = *(const f16x8*)&Ks[cur][(r << 7) + ((((kq << 2) + lq) ^ (r & 7)) << 3)];
          }
#pragma unroll
          for (int mi = 0; mi < 2; ++mi)
#pragma unroll
            for (int ni = 0; ni < 4; ++ni)
              sacc[mi][ni] = MFMA_16x16x32(qf[mi][kq], kf[ni], sacc[mi][ni]);
        }
        if (kv0 + 63 > wrow0) {
#pragma unroll
          for (int mi = 0; mi < 2; ++mi)
#pragma unroll
            for (int ni = 0; ni < 4; ++ni)
#pragma unroll
              for (int r = 0; r < 4; ++r) {
                const int qr = wrow0 + (mi << 4) + (lq << 2) + r;
                const int kv = kv0 + (ni << 4) + lh;
                if (kv > qr) sacc[mi][ni][r] = -1e30f;
              }
        }
        float scl[2][4], rsum[2][4];
#pragma unroll
        for (int mi = 0; mi < 2; ++mi)
#pragma unroll
          for (int r = 0; r < 4; ++r) {
            float v = fmaxf(fmaxf(sacc[mi][0][r], sacc[mi][1][r]),
                            fmaxf(sacc[mi][2][r], sacc[mi][3][r]));
            v = fmaxf(v, __shfl_xor(v, 1));
            v = fmaxf(v, __shfl_xor(v, 2));
            v = fmaxf(v, __shfl_xor(v, 4));
            v = fmaxf(v, __shfl_xor(v, 8));
            const float mnew = fmaxf(mrun[mi][r], v);
            scl[mi][r] = __expf(mrun[mi][r] - mnew);
            mrun[mi][r] = mnew;
            rsum[mi][r] = 0.f;
          }
#pragma unroll
        for (int mi = 0; mi < 2; ++mi)
#pragma unroll
          for (int ni = 0; ni < 4; ++ni)
#pragma unroll
            for (int r = 0; r < 4; ++r) {
              const float p = __expf(sacc[mi][ni][r] - mrun[mi][r]);
              rsum[mi][r] += p;
              Ps[w][((mi << 4) + (lq << 2) + r) * 72 + (ni << 4) + lh] = (f16)p;
            }
#pragma unroll
        for (int mi = 0; mi < 2; ++mi)
#pragma unroll
          for (int r = 0; r < 4; ++r) {
            float s = rsum[mi][r];
            s += __shfl_xor(s, 1);
            s += __shfl_xor(s, 2);
            s += __shfl_xor(s, 4);
            s += __shfl_xor(s, 8);
            lrun[mi][r] = lrun[mi][r] * scl[mi][r] + s;
          }
#pragma unroll
        for (int mi = 0; mi < 2; ++mi)
#pragma unroll
          for (int nd = 0; nd < 8; ++nd)
#pragma unroll
            for (int r = 0; r < 4; ++r) oacc[mi][nd][r] *= scl[mi][r];
      }

      if (more) asm volatile("s_waitcnt vmcnt(4)" ::: "memory");  // V retired
      else      asm volatile("s_waitcnt vmcnt(0)" ::: "memory");
      __builtin_amdgcn_s_barrier();                  // Vs visible

      if (active) {
#pragma unroll
        for (int kp = 0; kp < 2; ++kp) {
          f16x8 pf[2];
#pragma unroll
          for (int mi = 0; mi < 2; ++mi)
            pf[mi] = *(const f16x8*)&Ps[w][((mi << 4) + lh) * 72 + (kp << 5) + (lq << 3)];
#pragma unroll
          for (int nd = 0; nd < 8; ++nd) {
            const int r = (nd << 4) + lh;
            const f16x8 vf = *(const f16x8*)&Vs[(r << 6) + ((((kp << 2) + lq) ^ (r & 7)) << 3)];
#pragma unroll
            for (int mi = 0; mi < 2; ++mi)
              oacc[mi][nd] = MFMA_16x16x32(pf[mi], vf, oacc[mi][nd]);
          }
        }
      }
      asm volatile("" ::: "memory");
      __builtin_amdgcn_s_barrier();                  // readers done before overwrite
    }
#pragma unroll
    for (int mi = 0; mi < 2; ++mi)
#pragma unroll
      for (int nd = 0; nd < 8; ++nd)
#pragma unroll
        for (int r = 0; r < 4; ++r) {
          const int qr = wrow0 + (mi << 4) + (lq << 2) + r;
          const size_t off = (size_t)(b * L + qr) * E + h * HD + (nd << 4) + lh;
          X2[off] = (f16)(oacc[mi][nd][r] / lrun[mi][r] + Xres[off]);
        }
  }
}

// ---------------------------------------------------------------------------
extern "C" void kernel_launch(void* const* d_in, const int* in_sizes, int n_in,
                              void* d_out, int out_size, void* d_ws, size_t ws_size,
                              hipStream_t stream) {
  const float* x    = (const float*)d_in[0];
  const float* g    = (const float*)d_in[1];
  const float* wq   = (const float*)d_in[2];
  const float* wk   = (const float*)d_in[3];
  const float* wv   = (const float*)d_in[4];
  const float* w1   = (const float*)d_in[5];
  const float* b1   = (const float*)d_in[6];
  const float* wgp  = (const float*)d_in[7];
  const float* bg   = (const float*)d_in[8];
  const float* wl   = (const float*)d_in[9];
  const float* bl   = (const float*)d_in[10];
  const float* beta = (const float*)d_in[11];
  const float* w2   = (const float*)d_in[12];
  const float* b2   = (const float*)d_in[13];

  constexpr size_t MB = 1ull << 20;
  char* ws = (char*)d_ws;
  // ws layout (MB):
  //  0..32  wT (QKV convTs use 0..24; qcnt@31 untouched until post-attn convTs)
  //  32..33 Dt rope table
  //  33..49 hbuf
  //  49..65 qbuf   | a1 (49..81) after attention
  //  65..81 kbuf   |
  //  81..97 vbuf   | sbuf (81..113) after attention
  //  97..113 vtb   |
  //  113..129 x2h (f16 residual)
  //  145..177 act
  f16*   wT   = (f16*)(ws + 0 * MB);
  int*   qcnt = (int*)(ws + 31 * MB);
  float* Dt   = (float*)(ws + 32 * MB);
  f16*   hbuf = (f16*)(ws + 33 * MB);
  f16*   qkv  = (f16*)(ws + 49 * MB);   // q|k|v, 16MB segments (qbuf/kbuf/vbuf)
  f16*   vbuf = (f16*)(ws + 81 * MB);
  f16*   vtb  = (f16*)(ws + 97 * MB);
  f16*   x2h  = (f16*)(ws + 113 * MB);
  f16*   a1   = (f16*)(ws + 49 * MB);   // reuse q+k after attention
  f16*   sbuf = (f16*)(ws + 81 * MB);   // reuse v+vt after attention
  f16*   act  = (f16*)(ws + 145 * MB);
  (void)ws_size; (void)n_in; (void)in_sizes; (void)out_size;

  const dim3 blk(256);
  const float qscale = 0.08838834764831845f;  // 1/sqrt(128)

  rope_tab_k<<<2048, 128, 0, stream>>>(Dt);
  rmsnorm_k<<<4096, blk, 0, stream>>>(x, g, hbuf);
  hipMemsetAsync(qcnt, 0, 4, stream);

  // fused QKV: wT = [wq^T | wk^T | wv^T] (6144 x 2048), one N=6144 GEMM
  // (1536 blocks = exactly 2 full occupancy rounds @ 3 blocks/CU)
  convT_k<<<dim3(64, 64), blk, 0, stream>>>(wq, wT, 2048, 2048);
  convT_k<<<dim3(64, 64), blk, 0, stream>>>(wk, wT + (size_t)2048 * 2048, 2048, 2048);
  convT_k<<<dim3(64, 64), blk, 0, stream>>>(wv, wT + (size_t)4096 * 2048, 2048, 2048);
  gemm_k<6><<<dim3(48, 32), blk, 0, stream>>>(hbuf, wT, qkv, 4096, 6144, 2048,
                                              nullptr, Dt, nullptr, qscale);
  vtrans_k<<<dim3(64, 4, 32), blk, 0, stream>>>(vbuf, vtb);

  attn_k<<<384, blk, 0, stream>>>(qkv, qkv + (size_t)8388608, vtb, x, x2h, qcnt);

  rmsnorm_h_k<<<4096, blk, 0, stream>>>(x2h, g, hbuf);

  // MLP on 256^2 8-phase (round-4 exact, 16x16x32)
  convT_k<<<dim3(128, 64), blk, 0, stream>>>(w1, wT, 2048, 4096);
  gemm256_k<2><<<dim3(16, 16), 512, 0, stream>>>(hbuf, wT, a1, 4096, 4096, 2048,
                                                 b1, nullptr, nullptr);
  convT_k<<<dim3(128, 128), blk, 0, stream>>>(wgp, wT, 4096, 4096);
  gemm256_k<3><<<dim3(16, 16), 512, 0, stream>>>(a1, wT, sbuf, 4096, 4096, 4096,
                                                 bg, nullptr, beta);
  convT_k<<<dim3(128, 128), blk, 0, stream>>>(wl, wT, 4096, 4096);
  gemm256_k<4><<<dim3(16, 16), 512, 0, stream>>>(a1, wT, act, 4096, 4096, 4096,
                                                 bl, sbuf, nullptr);
  // out = act @ w2 + b2 + x2  (128^2 @ 3 blocks/CU)
  convT_k<<<dim3(64, 128), blk, 0, stream>>>(w2, wT, 4096, 2048);
  gemm_k<5><<<dim3(16, 32), blk, 0, stream>>>(act, wT, (float*)d_out, 4096, 2048, 4096,
                                              b2, nullptr, x2h, 1.0f);
}

// Round 14
// 718.175 us; speedup vs baseline: 1.1114x; 1.0075x over previous
//
#include <hip/hip_runtime.h>
#include <cstdint>
#include <math.h>

// ---------------------------------------------------------------------------
// LlamaSelfAttentionBlock: rmsnorm -> QKV (rope-diag) -> causal attn -> +res
//                          -> rmsnorm -> w1+b1 -> silu(beta*gate)*lin -> w2+b2 -> +res
// fp16 MFMA (16x16x32), f32 accumulate. B=2,L=2048,E=2048,H=16,hd=128,F=4096.
// Round 14: wg+wl GEMMs FUSED into one gemm256 dispatch over a packed weight
// [wg blk j 128 rows | wl blk j 128 rows] -> inner loop identical to round-4
// gemm256; epilogue: lin-waves stash lin+bl in LDS, gate-waves apply
// silu(beta*(gate+bg))*lin -> act. Kills sbuf round-trip + 2nd A-panel fetch.
// QKV fused N=6144 gemm_k (round 13). attn: round-10 counted-vmcnt pipeline.
// ---------------------------------------------------------------------------

typedef _Float16 f16;
typedef _Float16 f16x8 __attribute__((ext_vector_type(8)));
typedef _Float16 f16x4 __attribute__((ext_vector_type(4)));
typedef float    f32x4 __attribute__((ext_vector_type(4)));

#define MFMA_16x16x32(a, b, c) __builtin_amdgcn_mfma_f32_16x16x32_f16(a, b, c, 0, 0, 0)

__device__ __forceinline__ void gload_lds16(const void* g, void* lds) {
  __builtin_amdgcn_global_load_lds(
      (__attribute__((address_space(1))) void*)(uintptr_t)g,
      (__attribute__((address_space(3))) void*)(unsigned)(uintptr_t)lds,
      16, 0, 0);
}

// ---------------------------------------------------------------------------
// f32 [K][N] -> fp16 [N][K] transpose+convert (32x32 LDS tile)
// ---------------------------------------------------------------------------
__global__ void convT_k(const float* __restrict__ W, f16* __restrict__ Wt,
                        int K, int N) {
  __shared__ float tile[32][33];
  const int n0 = blockIdx.x << 5, k0 = blockIdx.y << 5;
  const int t = threadIdx.x;
  const int r = t >> 3, c4 = (t & 7) << 2;
  const f32x4 v = *(const f32x4*)(W + (size_t)(k0 + r) * N + n0 + c4);
  tile[r][c4 + 0] = v[0]; tile[r][c4 + 1] = v[1];
  tile[r][c4 + 2] = v[2]; tile[r][c4 + 3] = v[3];
  __syncthreads();
  f16x4 o;
  o[0] = (f16)tile[c4 + 0][r]; o[1] = (f16)tile[c4 + 1][r];
  o[2] = (f16)tile[c4 + 2][r]; o[3] = (f16)tile[c4 + 3][r];
  *(f16x4*)(Wt + (size_t)(n0 + r) * K + k0 + c4) = o;
}

// Same transpose, but output rows remapped into 256-row packed blocks:
// packed_row = (n>>7)*256 + off + (n&127). off=0 for wg, 128 for wl.
__global__ void convT_pack_k(const float* __restrict__ W, f16* __restrict__ Wt,
                             int K, int N, int off) {
  __shared__ float tile[32][33];
  const int n0 = blockIdx.x << 5, k0 = blockIdx.y << 5;
  const int t = threadIdx.x;
  const int r = t >> 3, c4 = (t & 7) << 2;
  const f32x4 v = *(const f32x4*)(W + (size_t)(k0 + r) * N + n0 + c4);
  tile[r][c4 + 0] = v[0]; tile[r][c4 + 1] = v[1];
  tile[r][c4 + 2] = v[2]; tile[r][c4 + 3] = v[3];
  __syncthreads();
  f16x4 o;
  o[0] = (f16)tile[c4 + 0][r]; o[1] = (f16)tile[c4 + 1][r];
  o[2] = (f16)tile[c4 + 2][r]; o[3] = (f16)tile[c4 + 3][r];
  const int n = n0 + r;
  const int pr = ((n >> 7) << 8) + off + (n & 127);
  *(f16x4*)(Wt + (size_t)pr * K + k0 + c4) = o;
}

// ---------------------------------------------------------------------------
// rope diag table: D[l][d] = cos(l * 10000^(-2*(d/2)/128)), f32 [2048][128]
// ---------------------------------------------------------------------------
__global__ void rope_tab_k(float* __restrict__ Dt) {
  const int l = blockIdx.x, d = threadIdx.x;
  const float th = __expf(-0.0719557841f * (float)(d & ~1));
  Dt[(l << 7) + d] = cosf((float)l * th);
}

// ---------------------------------------------------------------------------
// RMSNorm (f32 input): one block (256 thr) per row of 2048
// ---------------------------------------------------------------------------
__global__ void rmsnorm_k(const float* __restrict__ X, const float* __restrict__ G,
                          f16* __restrict__ H) {
  __shared__ float red[4];
  const int row = blockIdx.x, t = threadIdx.x;
  const float* xp = X + ((size_t)row << 11) + (t << 3);
  const f32x4 v0 = *(const f32x4*)xp;
  const f32x4 v1 = *(const f32x4*)(xp + 4);
  float ss = v0[0]*v0[0] + v0[1]*v0[1] + v0[2]*v0[2] + v0[3]*v0[3]
           + v1[0]*v1[0] + v1[1]*v1[1] + v1[2]*v1[2] + v1[3]*v1[3];
#pragma unroll
  for (int m = 1; m < 64; m <<= 1) ss += __shfl_xor(ss, m);
  if ((t & 63) == 0) red[t >> 6] = ss;
  __syncthreads();
  const float tot = red[0] + red[1] + red[2] + red[3];
  const float rs = rsqrtf(tot * (1.f / 2048.f) + 1e-6f);
  const float* gp = G + (t << 3);
  const f32x4 g0 = *(const f32x4*)gp, g1 = *(const f32x4*)(gp + 4);
  f16x8 o;
  o[0] = (f16)(v0[0]*rs*g0[0]); o[1] = (f16)(v0[1]*rs*g0[1]);
  o[2] = (f16)(v0[2]*rs*g0[2]); o[3] = (f16)(v0[3]*rs*g0[3]);
  o[4] = (f16)(v1[0]*rs*g1[0]); o[5] = (f16)(v1[1]*rs*g1[1]);
  o[6] = (f16)(v1[2]*rs*g1[2]); o[7] = (f16)(v1[3]*rs*g1[3]);
  *(f16x8*)(H + ((size_t)row << 11) + (t << 3)) = o;
}

// ---------------------------------------------------------------------------
// RMSNorm (f16 input) — for the f16 x2 residual buffer
// ---------------------------------------------------------------------------
__global__ void rmsnorm_h_k(const f16* __restrict__ X, const float* __restrict__ G,
                            f16* __restrict__ H) {
  __shared__ float red[4];
  const int row = blockIdx.x, t = threadIdx.x;
  const f16x8 v = *(const f16x8*)(X + ((size_t)row << 11) + (t << 3));
  float f[8];
#pragma unroll
  for (int i = 0; i < 8; ++i) f[i] = (float)v[i];
  float ss = 0.f;
#pragma unroll
  for (int i = 0; i < 8; ++i) ss += f[i] * f[i];
#pragma unroll
  for (int m = 1; m < 64; m <<= 1) ss += __shfl_xor(ss, m);
  if ((t & 63) == 0) red[t >> 6] = ss;
  __syncthreads();
  const float tot = red[0] + red[1] + red[2] + red[3];
  const float rs = rsqrtf(tot * (1.f / 2048.f) + 1e-6f);
  const float* gp = G + (t << 3);
  const f32x4 g0 = *(const f32x4*)gp, g1 = *(const f32x4*)(gp + 4);
  f16x8 o;
#pragma unroll
  for (int i = 0; i < 4; ++i) o[i] = (f16)(f[i] * rs * g0[i]);
#pragma unroll
  for (int i = 0; i < 4; ++i) o[4 + i] = (f16)(f[4 + i] * rs * g1[i]);
  *(f16x8*)(H + ((size_t)row << 11) + (t << 3)) = o;
}

// ---------------------------------------------------------------------------
// per-head V transpose: V [B*L][E] -> Vt [B*H][128][2048]  (fp16)
// ---------------------------------------------------------------------------
__global__ void vtrans_k(const f16* __restrict__ V, f16* __restrict__ Vt) {
  __shared__ f16 tile[32][36];
  const int l0 = blockIdx.x << 5, d0 = blockIdx.y << 5, bh = blockIdx.z;
  const int b = bh >> 4, h = bh & 15;
  const int t = threadIdx.x;
  const int r = t >> 3, c4 = (t & 7) << 2;
  const f16x4 v = *(const f16x4*)(V + (size_t)((b << 11) + l0 + r) * 2048 + (h << 7) + d0 + c4);
  tile[r][c4 + 0] = v[0]; tile[r][c4 + 1] = v[1];
  tile[r][c4 + 2] = v[2]; tile[r][c4 + 3] = v[3];
  __syncthreads();
  f16x4 o;
  o[0] = tile[c4 + 0][r]; o[1] = tile[c4 + 1][r];
  o[2] = tile[c4 + 2][r]; o[3] = tile[c4 + 3][r];
  *(f16x4*)(Vt + (size_t)((bh << 7) + d0 + r) * 2048 + l0 + c4) = o;
}

// ---------------------------------------------------------------------------
// 256x256-tile 8-phase fp16 GEMM — round-4 inner loop (875 TF, 0 conflicts).
// EPI: 2=+bias -> f16
//      7=fused gate/lin: packed B (cols 0-127 gate, 128-255 lin per block);
//        lin-waves (wn>=2) stash lin+bias2 in LDS; gate-waves apply
//        silu(beta*(gate+bias))*lin -> f16 out with stride N/2.
// ---------------------------------------------------------------------------
template <int EPI>
__launch_bounds__(512, 2)
__global__ void gemm256_k(const f16* __restrict__ A, const f16* __restrict__ Bt,
                          void* __restrict__ Cout, int M, int N, int K,
                          const float* __restrict__ bias,
                          const float* __restrict__ bias2,
                          const float* __restrict__ betap) {
  __shared__ alignas(16) f16 lds[65536];  // [buf0 A|buf0 B|buf1 A|buf1 B] 128KiB
  const int t = threadIdx.x, lane = t & 63, w = t >> 6;
  const int wm = w >> 2, wn = w & 3;
  const int bm = blockIdx.y << 8, bn = blockIdx.x << 8;
  const int lh = lane & 15, lq = lane >> 4;
  const int NT = K >> 6;
  const int lrow = lane >> 3;                   // row within an 8-row issue
  const int lco  = ((lane & 7) ^ lrow) << 3;    // swizzled source chunk (f16)

  const f16* Agl = A  + (size_t)(bm + lrow) * K + lco;
  const f16* Bgl = Bt + (size_t)(bn + lrow) * K + lco;
  const int aw = w << 3;    // per-wave A staging base row
  const int bw = w << 4;    // per-wave B staging base row

  f32x4 acc[8][4] = {};
  f16x8 bf[4][2];

  auto stA = [&](int tile, int half) {  // half0: rows {aw, 128+aw}; half1: +64
    const int d = (tile & 1) << 15;
    const int k0 = tile << 6;
    const int r0 = aw + (half << 6);
    gload_lds16(Agl + (size_t)r0 * K + k0, (void*)&lds[d + r0 * 64]);
    gload_lds16(Agl + (size_t)(r0 + 128) * K + k0, (void*)&lds[d + (r0 + 128) * 64]);
  };
  auto stB = [&](int tile, int half) {  // half0: rows {bw, bw+8}; half1: +128
    const int d = ((tile & 1) << 15) + 16384;
    const int k0 = tile << 6;
    const int r0 = bw + (half << 7);
    gload_lds16(Bgl + (size_t)r0 * K + k0, (void*)&lds[d + r0 * 64]);
    gload_lds16(Bgl + (size_t)(r0 + 8) * K + k0, (void*)&lds[d + (r0 + 8) * 64]);
  };
  auto ldA = [&](int d, int mi, int kk) {
    const int r = (wm << 7) + (mi << 4) + lh;
    return *(const f16x8*)&lds[(d << 15) + r * 64 + ((((kk << 2) + lq) ^ (lh & 7)) << 3)];
  };
  auto ldB = [&](int d, int ni, int kk) {
    const int r = (wn << 6) + (ni << 4) + lh;
    return *(const f16x8*)&lds[(d << 15) + 16384 + r * 64 + ((((kk << 2) + lq) ^ (lh & 7)) << 3)];
  };

  // prologue: tile0 fully + tile1 minus A-half1 (14 loads; first 8 = tile0)
  stB(0, 0); stB(0, 1); stA(0, 0); stA(0, 1);
  stB(1, 0); stB(1, 1); stA(1, 0);
  asm volatile("s_waitcnt vmcnt(6)" ::: "memory");
  __builtin_amdgcn_s_barrier();

  for (int tt = 0; tt < NT; tt += 2) {
    const bool pf = (tt + 2 < NT);
#pragma unroll
    for (int hf = 0; hf < 2; ++hf) {  // hf0: tile tt (buf0); hf1: tile tt+1 (buf1)
#pragma unroll
      for (int ph = 0; ph < 4; ++ph) {
        f16x8 a0k0 = ldA(hf, 2 * ph, 0),     a0k1 = ldA(hf, 2 * ph, 1);
        f16x8 a1k0 = ldA(hf, 2 * ph + 1, 0), a1k1 = ldA(hf, 2 * ph + 1, 1);
        if (ph == 0) {
#pragma unroll
          for (int ni = 0; ni < 4; ++ni) {
            bf[ni][0] = ldB(hf, ni, 0); bf[ni][1] = ldB(hf, ni, 1);
          }
        }
        if (hf == 0) {
          if (ph == 0) stA(tt + 1, 1);
          else if (ph == 1) { if (pf) stB(tt + 2, 0); }
          else if (ph == 2) { if (pf) stB(tt + 2, 1); }
          else              { if (pf) stA(tt + 2, 0); }
        } else {
          if (ph == 0)      { if (pf) stA(tt + 2, 1); }
          else if (ph == 1) { if (pf) stB(tt + 3, 0); }
          else if (ph == 2) { if (pf) stB(tt + 3, 1); }
          else              { if (pf) stA(tt + 3, 0); }
        }
        __builtin_amdgcn_s_barrier();
        __builtin_amdgcn_s_setprio(1);
#pragma unroll
        for (int ni = 0; ni < 4; ++ni) {
          acc[2 * ph][ni]     = MFMA_16x16x32(a0k0, bf[ni][0], acc[2 * ph][ni]);
          acc[2 * ph][ni]     = MFMA_16x16x32(a0k1, bf[ni][1], acc[2 * ph][ni]);
          acc[2 * ph + 1][ni] = MFMA_16x16x32(a1k0, bf[ni][0], acc[2 * ph + 1][ni]);
          acc[2 * ph + 1][ni] = MFMA_16x16x32(a1k1, bf[ni][1], acc[2 * ph + 1][ni]);
        }
        __builtin_amdgcn_s_setprio(0);
        if (ph == 3) {
          if (hf == 0) {
            if (pf) asm volatile("s_waitcnt vmcnt(6)" ::: "memory");
            else    asm volatile("s_waitcnt vmcnt(0)" ::: "memory");
          } else if (pf) {
            asm volatile("s_waitcnt vmcnt(6)" ::: "memory");
          }
        }
        __builtin_amdgcn_s_barrier();
      }
    }
  }

  if (EPI == 2) {
#pragma unroll
    for (int mi = 0; mi < 8; ++mi) {
#pragma unroll
      for (int ni = 0; ni < 4; ++ni) {
#pragma unroll
        for (int r = 0; r < 4; ++r) {
          const int grow = bm + (wm << 7) + (mi << 4) + (lq << 2) + r;
          const int gcol = bn + (wn << 6) + (ni << 4) + lh;
          ((f16*)Cout)[(size_t)grow * N + gcol] = (f16)(acc[mi][ni][r] + bias[gcol]);
        }
      }
    }
  } else {  // EPI == 7: fused gate/lin
    f16* linlds = (f16*)lds;            // 256 x 136 f16 = 68KB, reuse LDS
    const int ncol0 = bn >> 1;          // output col base (out stride N/2)
    const int Nout = N >> 1;
    if (wn >= 2) {
#pragma unroll
      for (int mi = 0; mi < 8; ++mi)
#pragma unroll
        for (int ni = 0; ni < 4; ++ni)
#pragma unroll
          for (int r = 0; r < 4; ++r) {
            const int row = (wm << 7) + (mi << 4) + (lq << 2) + r;
            const int col = ((wn - 2) << 6) + (ni << 4) + lh;
            linlds[row * 136 + col] = (f16)(acc[mi][ni][r] + bias2[ncol0 + col]);
          }
    }
    __syncthreads();
    if (wn < 2) {
      const float be = betap[0];
#pragma unroll
      for (int mi = 0; mi < 8; ++mi)
#pragma unroll
        for (int ni = 0; ni < 4; ++ni)
#pragma unroll
          for (int r = 0; r < 4; ++r) {
            const int row = (wm << 7) + (mi << 4) + (lq << 2) + r;
            const int col = (wn << 6) + (ni << 4) + lh;
            const float v = acc[mi][ni][r] + bias[ncol0 + col];
            const float lin = (float)linlds[row * 136 + col];
            const float a = v / (1.f + __expf(-be * v)) * lin;
            ((f16*)Cout)[(size_t)(bm + row) * Nout + ncol0 + col] = (f16)a;
          }
    }
  }
}

// ---------------------------------------------------------------------------
// 128x128 GEMM (proven 16x16x32), 3 blocks/CU.
// EPI: 5=+bias,+auxh(f16 residual)->f32
//      6=fused QKV: seg=gcol>>11 (0=q rope*scale, 1=k rope, 2=v)
// ---------------------------------------------------------------------------
template <int EPI>
__launch_bounds__(256, 3)
__global__ void gemm_k(const f16* __restrict__ A, const f16* __restrict__ Bt,
                       void* __restrict__ Cout, int M, int N, int K,
                       const float* __restrict__ bias,
                       const float* __restrict__ auxf,
                       const f16* __restrict__ auxh,
                       float scale) {
  __shared__ alignas(16) f16 As[128 * 64];
  __shared__ alignas(16) f16 Bs[128 * 64];
  const int t = threadIdx.x;
  const int lane = t & 63;
  const int w = t >> 6;
  const int wm = w >> 1, wn = w & 1;
  const int bm = blockIdx.y << 7;
  const int bn = blockIdx.x << 7;
  const int lh = lane & 15, lq = lane >> 4;

  f32x4 acc[4][4] = {};

  for (int k0 = 0; k0 < K; k0 += 64) {
    __syncthreads();
#pragma unroll
    for (int i = 0; i < 4; ++i) {
      const int idx = i * 256 + (w << 6) + lane;
      const int row = idx >> 3, c = idx & 7;
      const int cs = (c ^ (row & 7)) << 3;
      gload_lds16(A + (size_t)(bm + row) * K + k0 + cs,
                  &As[(i * 256 + (w << 6)) << 3]);
      gload_lds16(Bt + (size_t)(bn + row) * K + k0 + cs,
                  &Bs[(i * 256 + (w << 6)) << 3]);
    }
    asm volatile("s_waitcnt vmcnt(0)" ::: "memory");
    __syncthreads();
#pragma unroll
    for (int kk = 0; kk < 2; ++kk) {
      f16x8 af[4], bfr[4];
#pragma unroll
      for (int mi = 0; mi < 4; ++mi) {
        const int r = (wm << 6) + (mi << 4) + lh;
        af[mi] = *(const f16x8*)&As[(r << 6) + ((((kk << 2) + lq) ^ (r & 7)) << 3)];
      }
#pragma unroll
      for (int ni = 0; ni < 4; ++ni) {
        const int r = (wn << 6) + (ni << 4) + lh;
        bfr[ni] = *(const f16x8*)&Bs[(r << 6) + ((((kk << 2) + lq) ^ (r & 7)) << 3)];
      }
#pragma unroll
      for (int mi = 0; mi < 4; ++mi)
#pragma unroll
        for (int ni = 0; ni < 4; ++ni)
          acc[mi][ni] = MFMA_16x16x32(af[mi], bfr[ni], acc[mi][ni]);
    }
  }

#pragma unroll
  for (int mi = 0; mi < 4; ++mi) {
#pragma unroll
    for (int ni = 0; ni < 4; ++ni) {
#pragma unroll
      for (int r = 0; r < 4; ++r) {
        const int grow = bm + (wm << 6) + (mi << 4) + (lq << 2) + r;
        const int gcol = bn + (wn << 6) + (ni << 4) + lh;
        float v = acc[mi][ni][r];
        if (EPI == 6) {
          const int seg = gcol >> 11, c = gcol & 2047;
          if (seg < 2) {
            const float f = auxf[((grow & 2047) << 7) + (c & 127)];
            v *= (seg == 0) ? scale * f : f;
          }
          ((f16*)Cout)[(size_t)seg * 8388608 + ((size_t)grow << 11) + c] = (f16)v;
        } else {
          ((float*)Cout)[(size_t)grow * N + gcol] = v + bias[gcol] + (float)auxh[(size_t)grow * N + gcol];
        }
      }
    }
  }
}

// ---------------------------------------------------------------------------
// Causal flash attention v3 (round-10 validated): work queue + counted-vmcnt
// pipeline. 384 blocks x 256 thr, 2 blocks/CU. X2 output f16.
// ---------------------------------------------------------------------------
__launch_bounds__(256, 2)
__global__ void attn_k(const f16* __restrict__ Q, const f16* __restrict__ Kb,
                       const f16* __restrict__ Vt, const float* __restrict__ Xres,
                       f16* __restrict__ X2, int* __restrict__ qcnt) {
  constexpr int L = 2048, E = 2048, HD = 128;
  __shared__ alignas(16) f16 Ks[2][64 * 128];
  __shared__ alignas(16) f16 Vs[128 * 64];
  __shared__ alignas(16) f16 Ps[4][32 * 72];
  __shared__ int s_item;

  const int t = threadIdx.x, lane = t & 63, w = t >> 6;
  const int lh = lane & 15, lq = lane >> 4;

  for (;;) {
    if (t == 0) s_item = atomicAdd(qcnt, 1);
    __syncthreads();                 // full drain: vmcnt accounting resets to 0
    const int item = s_item;
    if (item >= 512) return;
    const int bh = item & 31;                 // head-major within a q-band
    const int q0 = (15 - (item >> 5)) << 7;   // heaviest q-tiles first (LPT)
    const int b = bh >> 4, h = bh & 15;
    const int wrow0 = q0 + (w << 5);

    auto issueK = [&](int kv0, int buf) {  // 4 gload_lds -> Ks[buf]
#pragma unroll
      for (int i = 0; i < 4; ++i) {
        const int idx = i * 256 + (w << 6) + lane;
        const int row = idx >> 4, c = idx & 15;
        gload_lds16(Kb + (size_t)(b * L + kv0 + row) * E + h * HD + ((c ^ (row & 7)) << 3),
                    &Ks[buf][(i * 256 + (w << 6)) << 3]);
      }
    };
    auto issueV = [&](int kv0) {           // 4 gload_lds -> Vs
#pragma unroll
      for (int i = 0; i < 4; ++i) {
        const int idx = i * 256 + (w << 6) + lane;
        const int row = idx >> 3, c = idx & 7;
        gload_lds16(Vt + ((size_t)bh * HD + row) * L + kv0 + ((c ^ (row & 7)) << 3),
                    &Vs[(i * 256 + (w << 6)) << 3]);
      }
    };

    f16x8 qf[2][4];
#pragma unroll
    for (int mi = 0; mi < 2; ++mi) {
      const f16* qrow = Q + (size_t)(b * L + wrow0 + (mi << 4) + lh) * E + h * HD;
#pragma unroll
      for (int kq = 0; kq < 4; ++kq)
        qf[mi][kq] = *(const f16x8*)(qrow + (kq << 5) + (lq << 3));
    }
    asm volatile("s_waitcnt vmcnt(0)" ::: "memory");  // qf resident; count = 0

    f32x4 oacc[2][8] = {};
    float mrun[2][4], lrun[2][4];
#pragma unroll
    for (int mi = 0; mi < 2; ++mi)
#pragma unroll
      for (int r = 0; r < 4; ++r) { mrun[mi][r] = -1e30f; lrun[mi][r] = 0.f; }

    const int nt = (q0 + 128) >> 6;
    issueK(0, 0);                                    // outstanding: 4
    for (int it = 0; it < nt; ++it) {
      const int cur = it & 1;
      const int kv0 = it << 6;
      const bool more = (it + 1 < nt);
      issueV(kv0);                                   // outstanding: 8
      if (more) {
        issueK(kv0 + 64, cur ^ 1);                   // outstanding: 12
        asm volatile("s_waitcnt vmcnt(8)" ::: "memory");   // K[cur] retired
      } else {
        asm volatile("s_waitcnt vmcnt(4)" ::: "memory");
      }
      __builtin_amdgcn_s_barrier();                  // Ks[cur] visible

      const bool active = (kv0 <= wrow0 + 31);
      if (active) {
        f32x4 sacc[2][4] = {};
#pragma unroll
        for (int kq = 0; kq < 4; ++kq) {
          f16x8 kf[4];
#pragma unroll
          for (int ni = 0; ni < 4; ++ni) {
            const int r = (ni << 4) + lh;
            kf[ni] = *(const f16x8*)&Ks[cur][(r << 7) + ((((kq << 2) + lq) ^ (r & 7)) << 3)];
          }
#pragma unroll
          for (int mi = 0; mi < 2; ++mi)
#pragma unroll
            for (int ni = 0; ni < 4; ++ni)
              sacc[mi][ni] = MFMA_16x16x32(qf[mi][kq], kf[ni], sacc[mi][ni]);
        }
        if (kv0 + 63 > wrow0) {
#pragma unroll
          for (int mi = 0; mi < 2; ++mi)
#pragma unroll
            for (int ni = 0; ni < 4; ++ni)
#pragma unroll
              for (int r = 0; r < 4; ++r) {
                const int qr = wrow0 + (mi << 4) + (lq << 2) + r;
                const int kv = kv0 + (ni << 4) + lh;
                if (kv > qr) sacc[mi][ni][r] = -1e30f;
              }
        }
        float scl[2][4], rsum[2][4];
#pragma unroll
        for (int mi = 0; mi < 2; ++mi)
#pragma unroll
          for (int r = 0; r < 4; ++r) {
            float v = fmaxf(fmaxf(sacc[mi][0][r], sacc[mi][1][r]),
                            fmaxf(sacc[mi][2][r], sacc[mi][3][r]));
            v = fmaxf(v, __shfl_xor(v, 1));
            v = fmaxf(v, __shfl_xor(v, 2));
            v = fmaxf(v, __shfl_xor(v, 4));
            v = fmaxf(v, __shfl_xor(v, 8));
            const float mnew = fmaxf(mrun[mi][r], v);
            scl[mi][r] = __expf(mrun[mi][r] - mnew);
            mrun[mi][r] = mnew;
            rsum[mi][r] = 0.f;
          }
#pragma unroll
        for (int mi = 0; mi < 2; ++mi)
#pragma unroll
          for (int ni = 0; ni < 4; ++ni)
#pragma unroll
            for (int r = 0; r < 4; ++r) {
              const float p = __expf(sacc[mi][ni][r] - mrun[mi][r]);
              rsum[mi][r] += p;
              Ps[w][((mi << 4) + (lq << 2) + r) * 72 + (ni << 4) + lh] = (f16)p;
            }
#pragma unroll
        for (int mi = 0; mi < 2; ++mi)
#pragma unroll
          for (int r = 0; r < 4; ++r) {
            float s = rsum[mi][r];
            s += __shfl_xor(s, 1);
            s += __shfl_xor(s, 2);
            s += __shfl_xor(s, 4);
            s += __shfl_xor(s, 8);
            lrun[mi][r] = lrun[mi][r] * scl[mi][r] + s;
          }
#pragma unroll
        for (int mi = 0; mi < 2; ++mi)
#pragma unroll
          for (int nd = 0; nd < 8; ++nd)
#pragma unroll
            for (int r = 0; r < 4; ++r) oacc[mi][nd][r] *= scl[mi][r];
      }

      if (more) asm volatile("s_waitcnt vmcnt(4)" ::: "memory");  // V retired
      else      asm volatile("s_waitcnt vmcnt(0)" ::: "memory");
      __builtin_amdgcn_s_barrier();                  // Vs visible

      if (active) {
#pragma unroll
        for (int kp = 0; kp < 2; ++kp) {
          f16x8 pf[2];
#pragma unroll
          for (int mi = 0; mi < 2; ++mi)
            pf[mi] = *(const f16x8*)&Ps[w][((mi << 4) + lh) * 72 + (kp << 5) + (lq << 3)];
#pragma unroll
          for (int nd = 0; nd < 8; ++nd) {
            const int r = (nd << 4) + lh;
            const f16x8 vf = *(const f16x8*)&Vs[(r << 6) + ((((kp << 2) + lq) ^ (r & 7)) << 3)];
#pragma unroll
            for (int mi = 0; mi < 2; ++mi)
              oacc[mi][nd] = MFMA_16x16x32(pf[mi], vf, oacc[mi][nd]);
          }
        }
      }
      asm volatile("" ::: "memory");
      __builtin_amdgcn_s_barrier();                  // readers done before overwrite
    }
#pragma unroll
    for (int mi = 0; mi < 2; ++mi)
#pragma unroll
      for (int nd = 0; nd < 8; ++nd)
#pragma unroll
        for (int r = 0; r < 4; ++r) {
          const int qr = wrow0 + (mi << 4) + (lq << 2) + r;
          const size_t off = (size_t)(b * L + qr) * E + h * HD + (nd << 4) + lh;
          X2[off] = (f16)(oacc[mi][nd][r] / lrun[mi][r] + Xres[off]);
        }
  }
}

// ---------------------------------------------------------------------------
extern "C" void kernel_launch(void* const* d_in, const int* in_sizes, int n_in,
                              void* d_out, int out_size, void* d_ws, size_t ws_size,
                              hipStream_t stream) {
  const float* x    = (const float*)d_in[0];
  const float* g    = (const float*)d_in[1];
  const float* wq   = (const float*)d_in[2];
  const float* wk   = (const float*)d_in[3];
  const float* wv   = (const float*)d_in[4];
  const float* w1   = (const float*)d_in[5];
  const float* b1   = (const float*)d_in[6];
  const float* wgp  = (const float*)d_in[7];
  const float* bg   = (const float*)d_in[8];
  const float* wl   = (const float*)d_in[9];
  const float* bl   = (const float*)d_in[10];
  const float* beta = (const float*)d_in[11];
  const float* w2   = (const float*)d_in[12];
  const float* b2   = (const float*)d_in[13];

  constexpr size_t MB = 1ull << 20;
  char* ws = (char*)d_ws;
  // ws layout (MB), liveness-audited:
  //  0..64   wBIG: QKV wT (0..24) -> w1T (0..16) -> packed wGL (0..64) -> w2T (0..16)
  //  64..65  Dt rope table (exactly 1MB)
  //  65..66  qcnt (4B)
  //  66..82  hbuf
  //  82..130 qkv (q 82..98 | k 98..114 | v 114..130); a1 reuses 82..114 after attn
  //  114..146 act (reuses v+vtb after their death)
  //  130..146 vtb
  //  146..162 x2h (f16 residual)
  f16*   wBIG = (f16*)(ws + 0 * MB);
  float* Dt   = (float*)(ws + 64 * MB);
  int*   qcnt = (int*)(ws + 65 * MB);
  f16*   hbuf = (f16*)(ws + 66 * MB);
  f16*   qkv  = (f16*)(ws + 82 * MB);
  f16*   vbuf = (f16*)(ws + 114 * MB);
  f16*   vtb  = (f16*)(ws + 130 * MB);
  f16*   x2h  = (f16*)(ws + 146 * MB);
  f16*   a1   = (f16*)(ws + 82 * MB);
  f16*   act  = (f16*)(ws + 114 * MB);
  (void)ws_size; (void)n_in; (void)in_sizes; (void)out_size;

  const dim3 blk(256);
  const float qscale = 0.08838834764831845f;  // 1/sqrt(128)

  rope_tab_k<<<2048, 128, 0, stream>>>(Dt);
  rmsnorm_k<<<4096, blk, 0, stream>>>(x, g, hbuf);
  hipMemsetAsync(qcnt, 0, 4, stream);

  // fused QKV: wBIG = [wq^T | wk^T | wv^T] (6144 x 2048), one N=6144 GEMM
  convT_k<<<dim3(64, 64), blk, 0, stream>>>(wq, wBIG, 2048, 2048);
  convT_k<<<dim3(64, 64), blk, 0, stream>>>(wk, wBIG + (size_t)2048 * 2048, 2048, 2048);
  convT_k<<<dim3(64, 64), blk, 0, stream>>>(wv, wBIG + (size_t)4096 * 2048, 2048, 2048);
  gemm_k<6><<<dim3(48, 32), blk, 0, stream>>>(hbuf, wBIG, qkv, 4096, 6144, 2048,
                                              nullptr, Dt, nullptr, qscale);
  vtrans_k<<<dim3(64, 4, 32), blk, 0, stream>>>(vbuf, vtb);

  attn_k<<<384, blk, 0, stream>>>(qkv, qkv + (size_t)8388608, vtb, x, x2h, qcnt);

  rmsnorm_h_k<<<4096, blk, 0, stream>>>(x2h, g, hbuf);

  // a1 = h2 @ w1 + b1  (256^2 8-phase)
  convT_k<<<dim3(128, 64), blk, 0, stream>>>(w1, wBIG, 2048, 4096);
  gemm256_k<2><<<dim3(16, 16), 512, 0, stream>>>(hbuf, wBIG, a1, 4096, 4096, 2048,
                                                 b1, nullptr, nullptr);
  // fused gate/lin: packed wGL [8192][4096], one dispatch
  convT_pack_k<<<dim3(128, 128), blk, 0, stream>>>(wgp, wBIG, 4096, 4096, 0);
  convT_pack_k<<<dim3(128, 128), blk, 0, stream>>>(wl, wBIG, 4096, 4096, 128);
  gemm256_k<7><<<dim3(32, 16), 512, 0, stream>>>(a1, wBIG, act, 4096, 8192, 4096,
                                                 bg, bl, beta);
  // out = act @ w2 + b2 + x2  (128^2 @ 3 blocks/CU)
  convT_k<<<dim3(64, 128), blk, 0, stream>>>(w2, wBIG, 4096, 2048);
  gemm_k<5><<<dim3(16, 32), blk, 0, stream>>>(act, wBIG, (float*)d_out, 4096, 2048, 4096,
                                              b2, nullptr, x2h, 1.0f);
}

// Round 15
// 711.807 us; speedup vs baseline: 1.1213x; 1.0089x over previous
//
#include <hip/hip_runtime.h>
#include <cstdint>
#include <math.h>

// ---------------------------------------------------------------------------
// LlamaSelfAttentionBlock: rmsnorm -> QKV (rope-diag) -> causal attn -> +res
//                          -> rmsnorm -> w1+b1 -> silu(beta*gate)*lin -> w2+b2 -> +res
// fp16 MFMA (16x16x32), f32 accumulate. B=2,L=2048,E=2048,H=16,hd=128,F=4096.
// Round 15 (polish): batched convT dispatches (QKV z-grid; wg/wl pack z-grid);
// T5 setprio around attn MFMA clusters (m191: +4-7% attn). All GEMM/attn
// structure byte-identical to round 14 (best, 718us).
// ---------------------------------------------------------------------------

typedef _Float16 f16;
typedef _Float16 f16x8 __attribute__((ext_vector_type(8)));
typedef _Float16 f16x4 __attribute__((ext_vector_type(4)));
typedef float    f32x4 __attribute__((ext_vector_type(4)));

#define MFMA_16x16x32(a, b, c) __builtin_amdgcn_mfma_f32_16x16x32_f16(a, b, c, 0, 0, 0)

__device__ __forceinline__ void gload_lds16(const void* g, void* lds) {
  __builtin_amdgcn_global_load_lds(
      (__attribute__((address_space(1))) void*)(uintptr_t)g,
      (__attribute__((address_space(3))) void*)(unsigned)(uintptr_t)lds,
      16, 0, 0);
}

// ---------------------------------------------------------------------------
// Batched f32 [K][N] -> fp16 [N][K] transpose+convert: z selects one of 3
// sources (2048x2048 each), dest segment z*2048 rows.
// ---------------------------------------------------------------------------
__global__ void convT3_k(const float* __restrict__ W0, const float* __restrict__ W1,
                         const float* __restrict__ W2, f16* __restrict__ Wt) {
  __shared__ float tile[32][33];
  const int n0 = blockIdx.x << 5, k0 = blockIdx.y << 5, z = blockIdx.z;
  const float* W = (z == 0) ? W0 : (z == 1) ? W1 : W2;
  const int t = threadIdx.x;
  const int r = t >> 3, c4 = (t & 7) << 2;
  const f32x4 v = *(const f32x4*)(W + (size_t)(k0 + r) * 2048 + n0 + c4);
  tile[r][c4 + 0] = v[0]; tile[r][c4 + 1] = v[1];
  tile[r][c4 + 2] = v[2]; tile[r][c4 + 3] = v[3];
  __syncthreads();
  f16x4 o;
  o[0] = (f16)tile[c4 + 0][r]; o[1] = (f16)tile[c4 + 1][r];
  o[2] = (f16)tile[c4 + 2][r]; o[3] = (f16)tile[c4 + 3][r];
  *(f16x4*)(Wt + ((size_t)z * 2048 + n0 + r) * 2048 + k0 + c4) = o;
}

// Plain single transpose (w1, w2)
__global__ void convT_k(const float* __restrict__ W, f16* __restrict__ Wt,
                        int K, int N) {
  __shared__ float tile[32][33];
  const int n0 = blockIdx.x << 5, k0 = blockIdx.y << 5;
  const int t = threadIdx.x;
  const int r = t >> 3, c4 = (t & 7) << 2;
  const f32x4 v = *(const f32x4*)(W + (size_t)(k0 + r) * N + n0 + c4);
  tile[r][c4 + 0] = v[0]; tile[r][c4 + 1] = v[1];
  tile[r][c4 + 2] = v[2]; tile[r][c4 + 3] = v[3];
  __syncthreads();
  f16x4 o;
  o[0] = (f16)tile[c4 + 0][r]; o[1] = (f16)tile[c4 + 1][r];
  o[2] = (f16)tile[c4 + 2][r]; o[3] = (f16)tile[c4 + 3][r];
  *(f16x4*)(Wt + (size_t)(n0 + r) * K + k0 + c4) = o;
}

// Batched packing transpose for wg (z=0, off 0) / wl (z=1, off 128):
// packed_row = (n>>7)*256 + off + (n&127).
__global__ void convT_pack2_k(const float* __restrict__ Wg, const float* __restrict__ Wl,
                              f16* __restrict__ Wt) {
  __shared__ float tile[32][33];
  const int n0 = blockIdx.x << 5, k0 = blockIdx.y << 5, z = blockIdx.z;
  const float* W = z ? Wl : Wg;
  const int off = z << 7;
  const int t = threadIdx.x;
  const int r = t >> 3, c4 = (t & 7) << 2;
  const f32x4 v = *(const f32x4*)(W + (size_t)(k0 + r) * 4096 + n0 + c4);
  tile[r][c4 + 0] = v[0]; tile[r][c4 + 1] = v[1];
  tile[r][c4 + 2] = v[2]; tile[r][c4 + 3] = v[3];
  __syncthreads();
  f16x4 o;
  o[0] = (f16)tile[c4 + 0][r]; o[1] = (f16)tile[c4 + 1][r];
  o[2] = (f16)tile[c4 + 2][r]; o[3] = (f16)tile[c4 + 3][r];
  const int n = n0 + r;
  const int pr = ((n >> 7) << 8) + off + (n & 127);
  *(f16x4*)(Wt + (size_t)pr * 4096 + k0 + c4) = o;
}

// ---------------------------------------------------------------------------
// rope diag table: D[l][d] = cos(l * 10000^(-2*(d/2)/128)), f32 [2048][128]
// ---------------------------------------------------------------------------
__global__ void rope_tab_k(float* __restrict__ Dt) {
  const int l = blockIdx.x, d = threadIdx.x;
  const float th = __expf(-0.0719557841f * (float)(d & ~1));
  Dt[(l << 7) + d] = cosf((float)l * th);
}

// ---------------------------------------------------------------------------
// RMSNorm (f32 input): one block (256 thr) per row of 2048
// ---------------------------------------------------------------------------
__global__ void rmsnorm_k(const float* __restrict__ X, const float* __restrict__ G,
                          f16* __restrict__ H) {
  __shared__ float red[4];
  const int row = blockIdx.x, t = threadIdx.x;
  const float* xp = X + ((size_t)row << 11) + (t << 3);
  const f32x4 v0 = *(const f32x4*)xp;
  const f32x4 v1 = *(const f32x4*)(xp + 4);
  float ss = v0[0]*v0[0] + v0[1]*v0[1] + v0[2]*v0[2] + v0[3]*v0[3]
           + v1[0]*v1[0] + v1[1]*v1[1] + v1[2]*v1[2] + v1[3]*v1[3];
#pragma unroll
  for (int m = 1; m < 64; m <<= 1) ss += __shfl_xor(ss, m);
  if ((t & 63) == 0) red[t >> 6] = ss;
  __syncthreads();
  const float tot = red[0] + red[1] + red[2] + red[3];
  const float rs = rsqrtf(tot * (1.f / 2048.f) + 1e-6f);
  const float* gp = G + (t << 3);
  const f32x4 g0 = *(const f32x4*)gp, g1 = *(const f32x4*)(gp + 4);
  f16x8 o;
  o[0] = (f16)(v0[0]*rs*g0[0]); o[1] = (f16)(v0[1]*rs*g0[1]);
  o[2] = (f16)(v0[2]*rs*g0[2]); o[3] = (f16)(v0[3]*rs*g0[3]);
  o[4] = (f16)(v1[0]*rs*g1[0]); o[5] = (f16)(v1[1]*rs*g1[1]);
  o[6] = (f16)(v1[2]*rs*g1[2]); o[7] = (f16)(v1[3]*rs*g1[3]);
  *(f16x8*)(H + ((size_t)row << 11) + (t << 3)) = o;
}

// ---------------------------------------------------------------------------
// RMSNorm (f16 input) — for the f16 x2 residual buffer
// ---------------------------------------------------------------------------
__global__ void rmsnorm_h_k(const f16* __restrict__ X, const float* __restrict__ G,
                            f16* __restrict__ H) {
  __shared__ float red[4];
  const int row = blockIdx.x, t = threadIdx.x;
  const f16x8 v = *(const f16x8*)(X + ((size_t)row << 11) + (t << 3));
  float f[8];
#pragma unroll
  for (int i = 0; i < 8; ++i) f[i] = (float)v[i];
  float ss = 0.f;
#pragma unroll
  for (int i = 0; i < 8; ++i) ss += f[i] * f[i];
#pragma unroll
  for (int m = 1; m < 64; m <<= 1) ss += __shfl_xor(ss, m);
  if ((t & 63) == 0) red[t >> 6] = ss;
  __syncthreads();
  const float tot = red[0] + red[1] + red[2] + red[3];
  const float rs = rsqrtf(tot * (1.f / 2048.f) + 1e-6f);
  const float* gp = G + (t << 3);
  const f32x4 g0 = *(const f32x4*)gp, g1 = *(const f32x4*)(gp + 4);
  f16x8 o;
#pragma unroll
  for (int i = 0; i < 4; ++i) o[i] = (f16)(f[i] * rs * g0[i]);
#pragma unroll
  for (int i = 0; i < 4; ++i) o[4 + i] = (f16)(f[4 + i] * rs * g1[i]);
  *(f16x8*)(H + ((size_t)row << 11) + (t << 3)) = o;
}

// ---------------------------------------------------------------------------
// per-head V transpose: V [B*L][E] -> Vt [B*H][128][2048]  (fp16)
// ---------------------------------------------------------------------------
__global__ void vtrans_k(const f16* __restrict__ V, f16* __restrict__ Vt) {
  __shared__ f16 tile[32][36];
  const int l0 = blockIdx.x << 5, d0 = blockIdx.y << 5, bh = blockIdx.z;
  const int b = bh >> 4, h = bh & 15;
  const int t = threadIdx.x;
  const int r = t >> 3, c4 = (t & 7) << 2;
  const f16x4 v = *(const f16x4*)(V + (size_t)((b << 11) + l0 + r) * 2048 + (h << 7) + d0 + c4);
  tile[r][c4 + 0] = v[0]; tile[r][c4 + 1] = v[1];
  tile[r][c4 + 2] = v[2]; tile[r][c4 + 3] = v[3];
  __syncthreads();
  f16x4 o;
  o[0] = tile[c4 + 0][r]; o[1] = tile[c4 + 1][r];
  o[2] = tile[c4 + 2][r]; o[3] = tile[c4 + 3][r];
  *(f16x4*)(Vt + (size_t)((bh << 7) + d0 + r) * 2048 + l0 + c4) = o;
}

// ---------------------------------------------------------------------------
// 256x256-tile 8-phase fp16 GEMM — round-4 inner loop (875 TF, 0 conflicts).
// EPI: 2=+bias -> f16
//      7=fused gate/lin: packed B (cols 0-127 gate, 128-255 lin per block);
//        lin-waves (wn>=2) stash lin+bias2 in LDS; gate-waves apply
//        silu(beta*(gate+bias))*lin -> f16 out with stride N/2.
// ---------------------------------------------------------------------------
template <int EPI>
__launch_bounds__(512, 2)
__global__ void gemm256_k(const f16* __restrict__ A, const f16* __restrict__ Bt,
                          void* __restrict__ Cout, int M, int N, int K,
                          const float* __restrict__ bias,
                          const float* __restrict__ bias2,
                          const float* __restrict__ betap) {
  __shared__ alignas(16) f16 lds[65536];  // [buf0 A|buf0 B|buf1 A|buf1 B] 128KiB
  const int t = threadIdx.x, lane = t & 63, w = t >> 6;
  const int wm = w >> 2, wn = w & 3;
  const int bm = blockIdx.y << 8, bn = blockIdx.x << 8;
  const int lh = lane & 15, lq = lane >> 4;
  const int NT = K >> 6;
  const int lrow = lane >> 3;                   // row within an 8-row issue
  const int lco  = ((lane & 7) ^ lrow) << 3;    // swizzled source chunk (f16)

  const f16* Agl = A  + (size_t)(bm + lrow) * K + lco;
  const f16* Bgl = Bt + (size_t)(bn + lrow) * K + lco;
  const int aw = w << 3;    // per-wave A staging base row
  const int bw = w << 4;    // per-wave B staging base row

  f32x4 acc[8][4] = {};
  f16x8 bf[4][2];

  auto stA = [&](int tile, int half) {  // half0: rows {aw, 128+aw}; half1: +64
    const int d = (tile & 1) << 15;
    const int k0 = tile << 6;
    const int r0 = aw + (half << 6);
    gload_lds16(Agl + (size_t)r0 * K + k0, (void*)&lds[d + r0 * 64]);
    gload_lds16(Agl + (size_t)(r0 + 128) * K + k0, (void*)&lds[d + (r0 + 128) * 64]);
  };
  auto stB = [&](int tile, int half) {  // half0: rows {bw, bw+8}; half1: +128
    const int d = ((tile & 1) << 15) + 16384;
    const int k0 = tile << 6;
    const int r0 = bw + (half << 7);
    gload_lds16(Bgl + (size_t)r0 * K + k0, (void*)&lds[d + r0 * 64]);
    gload_lds16(Bgl + (size_t)(r0 + 8) * K + k0, (void*)&lds[d + (r0 + 8) * 64]);
  };
  auto ldA = [&](int d, int mi, int kk) {
    const int r = (wm << 7) + (mi << 4) + lh;
    return *(const f16x8*)&lds[(d << 15) + r * 64 + ((((kk << 2) + lq) ^ (lh & 7)) << 3)];
  };
  auto ldB = [&](int d, int ni, int kk) {
    const int r = (wn << 6) + (ni << 4) + lh;
    return *(const f16x8*)&lds[(d << 15) + 16384 + r * 64 + ((((kk << 2) + lq) ^ (lh & 7)) << 3)];
  };

  // prologue: tile0 fully + tile1 minus A-half1 (14 loads; first 8 = tile0)
  stB(0, 0); stB(0, 1); stA(0, 0); stA(0, 1);
  stB(1, 0); stB(1, 1); stA(1, 0);
  asm volatile("s_waitcnt vmcnt(6)" ::: "memory");
  __builtin_amdgcn_s_barrier();

  for (int tt = 0; tt < NT; tt += 2) {
    const bool pf = (tt + 2 < NT);
#pragma unroll
    for (int hf = 0; hf < 2; ++hf) {  // hf0: tile tt (buf0); hf1: tile tt+1 (buf1)
#pragma unroll
      for (int ph = 0; ph < 4; ++ph) {
        f16x8 a0k0 = ldA(hf, 2 * ph, 0),     a0k1 = ldA(hf, 2 * ph, 1);
        f16x8 a1k0 = ldA(hf, 2 * ph + 1, 0), a1k1 = ldA(hf, 2 * ph + 1, 1);
        if (ph == 0) {
#pragma unroll
          for (int ni = 0; ni < 4; ++ni) {
            bf[ni][0] = ldB(hf, ni, 0); bf[ni][1] = ldB(hf, ni, 1);
          }
        }
        if (hf == 0) {
          if (ph == 0) stA(tt + 1, 1);
          else if (ph == 1) { if (pf) stB(tt + 2, 0); }
          else if (ph == 2) { if (pf) stB(tt + 2, 1); }
          else              { if (pf) stA(tt + 2, 0); }
        } else {
          if (ph == 0)      { if (pf) stA(tt + 2, 1); }
          else if (ph == 1) { if (pf) stB(tt + 3, 0); }
          else if (ph == 2) { if (pf) stB(tt + 3, 1); }
          else              { if (pf) stA(tt + 3, 0); }
        }
        __builtin_amdgcn_s_barrier();
        __builtin_amdgcn_s_setprio(1);
#pragma unroll
        for (int ni = 0; ni < 4; ++ni) {
          acc[2 * ph][ni]     = MFMA_16x16x32(a0k0, bf[ni][0], acc[2 * ph][ni]);
          acc[2 * ph][ni]     = MFMA_16x16x32(a0k1, bf[ni][1], acc[2 * ph][ni]);
          acc[2 * ph + 1][ni] = MFMA_16x16x32(a1k0, bf[ni][0], acc[2 * ph + 1][ni]);
          acc[2 * ph + 1][ni] = MFMA_16x16x32(a1k1, bf[ni][1], acc[2 * ph + 1][ni]);
        }
        __builtin_amdgcn_s_setprio(0);
        if (ph == 3) {
          if (hf == 0) {
            if (pf) asm volatile("s_waitcnt vmcnt(6)" ::: "memory");
            else    asm volatile("s_waitcnt vmcnt(0)" ::: "memory");
          } else if (pf) {
            asm volatile("s_waitcnt vmcnt(6)" ::: "memory");
          }
        }
        __builtin_amdgcn_s_barrier();
      }
    }
  }

  if (EPI == 2) {
#pragma unroll
    for (int mi = 0; mi < 8; ++mi) {
#pragma unroll
      for (int ni = 0; ni < 4; ++ni) {
#pragma unroll
        for (int r = 0; r < 4; ++r) {
          const int grow = bm + (wm << 7) + (mi << 4) + (lq << 2) + r;
          const int gcol = bn + (wn << 6) + (ni << 4) + lh;
          ((f16*)Cout)[(size_t)grow * N + gcol] = (f16)(acc[mi][ni][r] + bias[gcol]);
        }
      }
    }
  } else {  // EPI == 7: fused gate/lin
    f16* linlds = (f16*)lds;            // 256 x 136 f16 = 68KB, reuse LDS
    const int ncol0 = bn >> 1;          // output col base (out stride N/2)
    const int Nout = N >> 1;
    if (wn >= 2) {
#pragma unroll
      for (int mi = 0; mi < 8; ++mi)
#pragma unroll
        for (int ni = 0; ni < 4; ++ni)
#pragma unroll
          for (int r = 0; r < 4; ++r) {
            const int row = (wm << 7) + (mi << 4) + (lq << 2) + r;
            const int col = ((wn - 2) << 6) + (ni << 4) + lh;
            linlds[row * 136 + col] = (f16)(acc[mi][ni][r] + bias2[ncol0 + col]);
          }
    }
    __syncthreads();
    if (wn < 2) {
      const float be = betap[0];
#pragma unroll
      for (int mi = 0; mi < 8; ++mi)
#pragma unroll
        for (int ni = 0; ni < 4; ++ni)
#pragma unroll
          for (int r = 0; r < 4; ++r) {
            const int row = (wm << 7) + (mi << 4) + (lq << 2) + r;
            const int col = (wn << 6) + (ni << 4) + lh;
            const float v = acc[mi][ni][r] + bias[ncol0 + col];
            const float lin = (float)linlds[row * 136 + col];
            const float a = v / (1.f + __expf(-be * v)) * lin;
            ((f16*)Cout)[(size_t)(bm + row) * Nout + ncol0 + col] = (f16)a;
          }
    }
  }
}

// ---------------------------------------------------------------------------
// 128x128 GEMM (proven 16x16x32), 3 blocks/CU.
// EPI: 5=+bias,+auxh(f16 residual)->f32
//      6=fused QKV: seg=gcol>>11 (0=q rope*scale, 1=k rope, 2=v)
// ---------------------------------------------------------------------------
template <int EPI>
__launch_bounds__(256, 3)
__global__ void gemm_k(const f16* __restrict__ A, const f16* __restrict__ Bt,
                       void* __restrict__ Cout, int M, int N, int K,
                       const float* __restrict__ bias,
                       const float* __restrict__ auxf,
                       const f16* __restrict__ auxh,
                       float scale) {
  __shared__ alignas(16) f16 As[128 * 64];
  __shared__ alignas(16) f16 Bs[128 * 64];
  const int t = threadIdx.x;
  const int lane = t & 63;
  const int w = t >> 6;
  const int wm = w >> 1, wn = w & 1;
  const int bm = blockIdx.y << 7;
  const int bn = blockIdx.x << 7;
  const int lh = lane & 15, lq = lane >> 4;

  f32x4 acc[4][4] = {};

  for (int k0 = 0; k0 < K; k0 += 64) {
    __syncthreads();
#pragma unroll
    for (int i = 0; i < 4; ++i) {
      const int idx = i * 256 + (w << 6) + lane;
      const int row = idx >> 3, c = idx & 7;
      const int cs = (c ^ (row & 7)) << 3;
      gload_lds16(A + (size_t)(bm + row) * K + k0 + cs,
                  &As[(i * 256 + (w << 6)) << 3]);
      gload_lds16(Bt + (size_t)(bn + row) * K + k0 + cs,
                  &Bs[(i * 256 + (w << 6)) << 3]);
    }
    asm volatile("s_waitcnt vmcnt(0)" ::: "memory");
    __syncthreads();
#pragma unroll
    for (int kk = 0; kk < 2; ++kk) {
      f16x8 af[4], bfr[4];
#pragma unroll
      for (int mi = 0; mi < 4; ++mi) {
        const int r = (wm << 6) + (mi << 4) + lh;
        af[mi] = *(const f16x8*)&As[(r << 6) + ((((kk << 2) + lq) ^ (r & 7)) << 3)];
      }
#pragma unroll
      for (int ni = 0; ni < 4; ++ni) {
        const int r = (wn << 6) + (ni << 4) + lh;
        bfr[ni] = *(const f16x8*)&Bs[(r << 6) + ((((kk << 2) + lq) ^ (r & 7)) << 3)];
      }
#pragma unroll
      for (int mi = 0; mi < 4; ++mi)
#pragma unroll
        for (int ni = 0; ni < 4; ++ni)
          acc[mi][ni] = MFMA_16x16x32(af[mi], bfr[ni], acc[mi][ni]);
    }
  }

#pragma unroll
  for (int mi = 0; mi < 4; ++mi) {
#pragma unroll
    for (int ni = 0; ni < 4; ++ni) {
#pragma unroll
      for (int r = 0; r < 4; ++r) {
        const int grow = bm + (wm << 6) + (mi << 4) + (lq << 2) + r;
        const int gcol = bn + (wn << 6) + (ni << 4) + lh;
        float v = acc[mi][ni][r];
        if (EPI == 6) {
          const int seg = gcol >> 11, c = gcol & 2047;
          if (seg < 2) {
            const float f = auxf[((grow & 2047) << 7) + (c & 127)];
            v *= (seg == 0) ? scale * f : f;
          }
          ((f16*)Cout)[(size_t)seg * 8388608 + ((size_t)grow << 11) + c] = (f16)v;
        } else {
          ((float*)Cout)[(size_t)grow * N + gcol] = v + bias[gcol] + (float)auxh[(size_t)grow * N + gcol];
        }
      }
    }
  }
}

// ---------------------------------------------------------------------------
// Causal flash attention v3 (round-10 validated) + T5 setprio on MFMA
// clusters. 384 blocks x 256 thr, 2 blocks/CU. X2 output f16.
// ---------------------------------------------------------------------------
__launch_bounds__(256, 2)
__global__ void attn_k(const f16* __restrict__ Q, const f16* __restrict__ Kb,
                       const f16* __restrict__ Vt, const float* __restrict__ Xres,
                       f16* __restrict__ X2, int* __restrict__ qcnt) {
  constexpr int L = 2048, E = 2048, HD = 128;
  __shared__ alignas(16) f16 Ks[2][64 * 128];
  __shared__ alignas(16) f16 Vs[128 * 64];
  __shared__ alignas(16) f16 Ps[4][32 * 72];
  __shared__ int s_item;

  const int t = threadIdx.x, lane = t & 63, w = t >> 6;
  const int lh = lane & 15, lq = lane >> 4;

  for (;;) {
    if (t == 0) s_item = atomicAdd(qcnt, 1);
    __syncthreads();                 // full drain: vmcnt accounting resets to 0
    const int item = s_item;
    if (item >= 512) return;
    const int bh = item & 31;                 // head-major within a q-band
    const int q0 = (15 - (item >> 5)) << 7;   // heaviest q-tiles first (LPT)
    const int b = bh >> 4, h = bh & 15;
    const int wrow0 = q0 + (w << 5);

    auto issueK = [&](int kv0, int buf) {  // 4 gload_lds -> Ks[buf]
#pragma unroll
      for (int i = 0; i < 4; ++i) {
        const int idx = i * 256 + (w << 6) + lane;
        const int row = idx >> 4, c = idx & 15;
        gload_lds16(Kb + (size_t)(b * L + kv0 + row) * E + h * HD + ((c ^ (row & 7)) << 3),
                    &Ks[buf][(i * 256 + (w << 6)) << 3]);
      }
    };
    auto issueV = [&](int kv0) {           // 4 gload_lds -> Vs
#pragma unroll
      for (int i = 0; i < 4; ++i) {
        const int idx = i * 256 + (w << 6) + lane;
        const int row = idx >> 3, c = idx & 7;
        gload_lds16(Vt + ((size_t)bh * HD + row) * L + kv0 + ((c ^ (row & 7)) << 3),
                    &Vs[(i * 256 + (w << 6)) << 3]);
      }
    };

    f16x8 qf[2][4];
#pragma unroll
    for (int mi = 0; mi < 2; ++mi) {
      const f16* qrow = Q + (size_t)(b * L + wrow0 + (mi << 4) + lh) * E + h * HD;
#pragma unroll
      for (int kq = 0; kq < 4; ++kq)
        qf[mi][kq] = *(const f16x8*)(qrow + (kq << 5) + (lq << 3));
    }
    asm volatile("s_waitcnt vmcnt(0)" ::: "memory");  // qf resident; count = 0

    f32x4 oacc[2][8] = {};
    float mrun[2][4], lrun[2][4];
#pragma unroll
    for (int mi = 0; mi < 2; ++mi)
#pragma unroll
      for (int r = 0; r < 4; ++r) { mrun[mi][r] = -1e30f; lrun[mi][r] = 0.f; }

    const int nt = (q0 + 128) >> 6;
    issueK(0, 0);                                    // outstanding: 4
    for (int it = 0; it < nt; ++it) {
      const int cur = it & 1;
      const int kv0 = it << 6;
      const bool more = (it + 1 < nt);
      issueV(kv0);                                   // outstanding: 8
      if (more) {
        issueK(kv0 + 64, cur ^ 1);                   // outstanding: 12
        asm volatile("s_waitcnt vmcnt(8)" ::: "memory");   // K[cur] retired
      } else {
        asm volatile("s_waitcnt vmcnt(4)" ::: "memory");
      }
      __builtin_amdgcn_s_barrier();                  // Ks[cur] visible

      const bool active = (kv0 <= wrow0 + 31);
      if (active) {
        f32x4 sacc[2][4] = {};
        __builtin_amdgcn_s_setprio(1);
#pragma unroll
        for (int kq = 0; kq < 4; ++kq) {
          f16x8 kf[4];
#pragma unroll
          for (int ni = 0; ni < 4; ++ni) {
            const int r = (ni << 4) + lh;
            kf[ni] = *(const f16x8*)&Ks[cur][(r << 7) + ((((kq << 2) + lq) ^ (r & 7)) << 3)];
          }
#pragma unroll
          for (int mi = 0; mi < 2; ++mi)
#pragma unroll
            for (int ni = 0; ni < 4; ++ni)
              sacc[mi][ni] = MFMA_16x16x32(qf[mi][kq], kf[ni], sacc[mi][ni]);
        }
        __builtin_amdgcn_s_setprio(0);
        if (kv0 + 63 > wrow0) {
#pragma unroll
          for (int mi = 0; mi < 2; ++mi)
#pragma unroll
            for (int ni = 0; ni < 4; ++ni)
#pragma unroll
              for (int r = 0; r < 4; ++r) {
                const int qr = wrow0 + (mi << 4) + (lq << 2) + r;
                const int kv = kv0 + (ni << 4) + lh;
                if (kv > qr) sacc[mi][ni][r] = -1e30f;
              }
        }
        float scl[2][4], rsum[2][4];
#pragma unroll
        for (int mi = 0; mi < 2; ++mi)
#pragma unroll
          for (int r = 0; r < 4; ++r) {
            float v = fmaxf(fmaxf(sacc[mi][0][r], sacc[mi][1][r]),
                            fmaxf(sacc[mi][2][r], sacc[mi][3][r]));
            v = fmaxf(v, __shfl_xor(v, 1));
            v = fmaxf(v, __shfl_xor(v, 2));
            v = fmaxf(v, __shfl_xor(v, 4));
            v = fmaxf(v, __shfl_xor(v, 8));
            const float mnew = fmaxf(mrun[mi][r], v);
            scl[mi][r] = __expf(mrun[mi][r] - mnew);
            mrun[mi][r] = mnew;
            rsum[mi][r] = 0.f;
          }
#pragma unroll
        for (int mi = 0; mi < 2; ++mi)
#pragma unroll
          for (int ni = 0; ni < 4; ++ni)
#pragma unroll
            for (int r = 0; r < 4; ++r) {
              const float p = __expf(sacc[mi][ni][r] - mrun[mi][r]);
              rsum[mi][r] += p;
              Ps[w][((mi << 4) + (lq << 2) + r) * 72 + (ni << 4) + lh] = (f16)p;
            }
#pragma unroll
        for (int mi = 0; mi < 2; ++mi)
#pragma unroll
          for (int r = 0; r < 4; ++r) {
            float s = rsum[mi][r];
            s += __shfl_xor(s, 1);
            s += __shfl_xor(s, 2);
            s += __shfl_xor(s, 4);
            s += __shfl_xor(s, 8);
            lrun[mi][r] = lrun[mi][r] * scl[mi][r] + s;
          }
#pragma unroll
        for (int mi = 0; mi < 2; ++mi)
#pragma unroll
          for (int nd = 0; nd < 8; ++nd)
#pragma unroll
            for (int r = 0; r < 4; ++r) oacc[mi][nd][r] *= scl[mi][r];
      }

      if (more) asm volatile("s_waitcnt vmcnt(4)" ::: "memory");  // V retired
      else      asm volatile("s_waitcnt vmcnt(0)" ::: "memory");
      __builtin_amdgcn_s_barrier();                  // Vs visible

      if (active) {
        __builtin_amdgcn_s_setprio(1);
#pragma unroll
        for (int kp = 0; kp < 2; ++kp) {
          f16x8 pf[2];
#pragma unroll
          for (int mi = 0; mi < 2; ++mi)
            pf[mi] = *(const f16x8*)&Ps[w][((mi << 4) + lh) * 72 + (kp << 5) + (lq << 3)];
#pragma unroll
          for (int nd = 0; nd < 8; ++nd) {
            const int r = (nd << 4) + lh;
            const f16x8 vf = *(const f16x8*)&Vs[(r << 6) + ((((kp << 2) + lq) ^ (r & 7)) << 3)];
#pragma unroll
            for (int mi = 0; mi < 2; ++mi)
              oacc[mi][nd] = MFMA_16x16x32(pf[mi], vf, oacc[mi][nd]);
          }
        }
        __builtin_amdgcn_s_setprio(0);
      }
      asm volatile("" ::: "memory");
      __builtin_amdgcn_s_barrier();                  // readers done before overwrite
    }
#pragma unroll
    for (int mi = 0; mi < 2; ++mi)
#pragma unroll
      for (int nd = 0; nd < 8; ++nd)
#pragma unroll
        for (int r = 0; r < 4; ++r) {
          const int qr = wrow0 + (mi << 4) + (lq << 2) + r;
          const size_t off = (size_t)(b * L + qr) * E + h * HD + (nd << 4) + lh;
          X2[off] = (f16)(oacc[mi][nd][r] / lrun[mi][r] + Xres[off]);
        }
  }
}

// ---------------------------------------------------------------------------
extern "C" void kernel_launch(void* const* d_in, const int* in_sizes, int n_in,
                              void* d_out, int out_size, void* d_ws, size_t ws_size,
                              hipStream_t stream) {
  const float* x    = (const float*)d_in[0];
  const float* g    = (const float*)d_in[1];
  const float* wq   = (const float*)d_in[2];
  const float* wk   = (const float*)d_in[3];
  const float* wv   = (const float*)d_in[4];
  const float* w1   = (const float*)d_in[5];
  const float* b1   = (const float*)d_in[6];
  const float* wgp  = (const float*)d_in[7];
  const float* bg   = (const float*)d_in[8];
  const float* wl   = (const float*)d_in[9];
  const float* bl   = (const float*)d_in[10];
  const float* beta = (const float*)d_in[11];
  const float* w2   = (const float*)d_in[12];
  const float* b2   = (const float*)d_in[13];

  constexpr size_t MB = 1ull << 20;
  char* ws = (char*)d_ws;
  // ws layout (MB), liveness-audited:
  //  0..64   wBIG: QKV wT (0..24) -> w1T (0..16) -> packed wGL (0..64) -> w2T (0..16)
  //  64..65  Dt rope table
  //  65..66  qcnt (4B)
  //  66..82  hbuf
  //  82..130 qkv (q 82..98 | k 98..114 | v 114..130); a1 reuses 82..114 after attn
  //  114..146 act (reuses v+vtb after their death)
  //  130..146 vtb
  //  146..162 x2h (f16 residual)
  f16*   wBIG = (f16*)(ws + 0 * MB);
  float* Dt   = (float*)(ws + 64 * MB);
  int*   qcnt = (int*)(ws + 65 * MB);
  f16*   hbuf = (f16*)(ws + 66 * MB);
  f16*   qkv  = (f16*)(ws + 82 * MB);
  f16*   vbuf = (f16*)(ws + 114 * MB);
  f16*   vtb  = (f16*)(ws + 130 * MB);
  f16*   x2h  = (f16*)(ws + 146 * MB);
  f16*   a1   = (f16*)(ws + 82 * MB);
  f16*   act  = (f16*)(ws + 114 * MB);
  (void)ws_size; (void)n_in; (void)in_sizes; (void)out_size;

  const dim3 blk(256);
  const float qscale = 0.08838834764831845f;  // 1/sqrt(128)

  rope_tab_k<<<2048, 128, 0, stream>>>(Dt);
  rmsnorm_k<<<4096, blk, 0, stream>>>(x, g, hbuf);
  hipMemsetAsync(qcnt, 0, 4, stream);

  // fused QKV: wBIG = [wq^T | wk^T | wv^T] (one batched transpose dispatch)
  convT3_k<<<dim3(64, 64, 3), blk, 0, stream>>>(wq, wk, wv, wBIG);
  gemm_k<6><<<dim3(48, 32), blk, 0, stream>>>(hbuf, wBIG, qkv, 4096, 6144, 2048,
                                              nullptr, Dt, nullptr, qscale);
  vtrans_k<<<dim3(64, 4, 32), blk, 0, stream>>>(vbuf, vtb);

  attn_k<<<384, blk, 0, stream>>>(qkv, qkv + (size_t)8388608, vtb, x, x2h, qcnt);

  rmsnorm_h_k<<<4096, blk, 0, stream>>>(x2h, g, hbuf);

  // a1 = h2 @ w1 + b1  (256^2 8-phase)
  convT_k<<<dim3(128, 64), blk, 0, stream>>>(w1, wBIG, 2048, 4096);
  gemm256_k<2><<<dim3(16, 16), 512, 0, stream>>>(hbuf, wBIG, a1, 4096, 4096, 2048,
                                                 b1, nullptr, nullptr);
  // fused gate/lin: packed wGL [8192][4096] (one batched pack dispatch)
  convT_pack2_k<<<dim3(128, 128, 2), blk, 0, stream>>>(wgp, wl, wBIG);
  gemm256_k<7><<<dim3(32, 16), 512, 0, stream>>>(a1, wBIG, act, 4096, 8192, 4096,
                                                 bg, bl, beta);
  // out = act @ w2 + b2 + x2  (128^2 @ 3 blocks/CU)
  convT_k<<<dim3(64, 128), blk, 0, stream>>>(w2, wBIG, 4096, 2048);
  gemm_k<5><<<dim3(16, 32), blk, 0, stream>>>(act, wBIG, (float*)d_out, 4096, 2048, 4096,
                                              b2, nullptr, x2h, 1.0f);
}